// Round 7
// baseline (9363.148 us; speedup 1.0000x reference)
//
#include <hip/hip_runtime.h>
#include <hip/hip_bf16.h>
#include <hip/hip_cooperative_groups.h>
#include <math.h>

namespace cg = cooperative_groups;

#define B_ 128
#define T_ 32
#define IN_ 512
#define H_ 512
#define M_ 16
#define WC_ 20
#define R_ 4
#define RW_ 80
#define NNIN_ 592
#define IFACE_ 163
#define IFP_ 192
#define K1P_ 1120
#define K2P_ 1024
#define KOP_ 608
#define CLIP_ 20.0f
#define EPS_ 1e-6f
#define DELTA_ 5e-6f
#define NT_ 65536   // total threads (256 blocks x 256)

typedef __bf16 bf16x8 __attribute__((ext_vector_type(8)));
typedef float f32x4 __attribute__((ext_vector_type(4)));

__device__ __forceinline__ float sigmoidf_(float x) { return 1.0f / (1.0f + expf(-x)); }
__device__ __forceinline__ float softplusf_(float x) {
    return fmaxf(x, 0.0f) + log1pf(expf(-fabsf(x)));
}
__device__ __forceinline__ void split2(float v, __bf16* hp, __bf16* lp) {
    __bf16 h = (__bf16)v;
    *hp = h;
    *lp = (__bf16)(v - (float)h);
}

struct Args {
    const float *x, *W_ih0, *W_hh0, *b_ih0, *b_hh0, *W_ih1, *W_hh1, *b_ih1, *b_hh1;
    const float *W_iface, *b_iface, *W_out, *b_out;
    float* out;
    __bf16 *a1h[2][2], *a1l[2][2];   // [layer][parity], stride K1P
    __bf16 *a2h[2][2], *a2l[2][2];   // [layer][parity], stride K2P
    __bf16 *yinh, *yinl;             // stride KOP
    float *cbuf, *memv, *linkv, *precv, *rwv, *wwv, *usagev, *ifacev;
    __bf16 *w1h[2], *w1l[2], *w2h[2], *w2l[2], *wifh[2], *wifl[2], *wouth, *woutl;
    float *biasif;
};

// ---------------------------------------------------------------------------
// Fused LSTM GEMM tile: 16x16 (batch x hidden) of all 4 gates, 4 waves split
// K, LDS reduce, wave0 runs LSTM pointwise epilogue.
// ---------------------------------------------------------------------------
__device__ __forceinline__ void gemm_lstm_tile(
    int tid, int jt, int mt, float* red,
    const __bf16* Ah, const __bf16* Al, int KS,
    const __bf16* Wh, const __bf16* Wl, int nsteps,
    const float* b1, const float* b2, float* cst,
    __bf16* d1h, __bf16* d1l, int st1, int off1,
    __bf16* d2h, __bf16* d2l, int st2, int off2, int clip2)
{
    const int wave = tid >> 6, lane = tid & 63;
    const int l15 = lane & 15, quad = lane >> 4;
    const int j0 = jt * 16, m0 = mt * 16;

    f32x4 acc[4];
    #pragma unroll
    for (int g = 0; g < 4; ++g)
        #pragma unroll
        for (int i = 0; i < 4; ++i) acc[g][i] = 0.f;

    const int ks = (wave * nsteps) >> 2;
    const int ke = ((wave + 1) * nsteps) >> 2;

    size_t aoff = (size_t)(m0 + l15) * KS + ks * 32 + quad * 8;
    size_t woff[4];
    #pragma unroll
    for (int g = 0; g < 4; ++g)
        woff[g] = (size_t)(g * 512 + j0 + l15) * KS + ks * 32 + quad * 8;

    for (int s = ks; s < ke; ++s) {
        bf16x8 ah = *(const bf16x8*)(Ah + aoff);
        bf16x8 al = *(const bf16x8*)(Al + aoff);
        aoff += 32;
        #pragma unroll
        for (int g = 0; g < 4; ++g) {
            bf16x8 wh = *(const bf16x8*)(Wh + woff[g]);
            bf16x8 wl = *(const bf16x8*)(Wl + woff[g]);
            woff[g] += 32;
            acc[g] = __builtin_amdgcn_mfma_f32_16x16x32_bf16(ah, wh, acc[g], 0, 0, 0);
            acc[g] = __builtin_amdgcn_mfma_f32_16x16x32_bf16(al, wh, acc[g], 0, 0, 0);
            acc[g] = __builtin_amdgcn_mfma_f32_16x16x32_bf16(ah, wl, acc[g], 0, 0, 0);
        }
    }

    if (wave > 0) {
        #pragma unroll
        for (int g = 0; g < 4; ++g)
            #pragma unroll
            for (int r = 0; r < 4; ++r)
                red[((g * 4 + r) * 3 + (wave - 1)) * 64 + lane] = acc[g][r];
    }
    __syncthreads();
    if (wave == 0) {
        const int col = j0 + l15;
        float bg[4];
        #pragma unroll
        for (int g = 0; g < 4; ++g) bg[g] = b1[g * 512 + col] + b2[g * 512 + col];
        #pragma unroll
        for (int r = 0; r < 4; ++r) {
            const int m = m0 + quad * 4 + r;
            float gv[4];
            #pragma unroll
            for (int g = 0; g < 4; ++g) {
                int i = g * 4 + r;
                gv[g] = acc[g][r] + red[(i * 3 + 0) * 64 + lane] + red[(i * 3 + 1) * 64 + lane]
                      + red[(i * 3 + 2) * 64 + lane] + bg[g];
            }
            float cold = cst[m * H_ + col];
            float cn = sigmoidf_(gv[1]) * cold + sigmoidf_(gv[0]) * tanhf(gv[2]);
            cst[m * H_ + col] = cn;
            float h = sigmoidf_(gv[3]) * tanhf(cn);
            split2(h, &d1h[(size_t)m * st1 + off1 + col], &d1l[(size_t)m * st1 + off1 + col]);
            float h2 = clip2 ? fminf(fmaxf(h, -CLIP_), CLIP_) : h;
            split2(h2, &d2h[(size_t)m * st2 + off2 + col], &d2l[(size_t)m * st2 + off2 + col]);
        }
    }
}

// ---------------------------------------------------------------------------
// Plain GEMM tile (iface / out): 16x16, 4 waves split K, fp32 + bias out
// ---------------------------------------------------------------------------
__device__ __forceinline__ void gemm_plain_tile(
    int tid, int nt, int mt, float* red,
    const __bf16* Ah, const __bf16* Al, int AS,
    const __bf16* Wh, const __bf16* Wl, int WS,
    int nsteps, const float* bias, float* C, int ldc)
{
    const int wave = tid >> 6, lane = tid & 63;
    const int l15 = lane & 15, quad = lane >> 4;
    const int n0 = nt * 16, m0 = mt * 16;

    f32x4 acc;
    #pragma unroll
    for (int i = 0; i < 4; ++i) acc[i] = 0.f;

    const int ks = (wave * nsteps) >> 2;
    const int ke = ((wave + 1) * nsteps) >> 2;

    size_t aoff = (size_t)(m0 + l15) * AS + ks * 32 + quad * 8;
    size_t woff = (size_t)(n0 + l15) * WS + ks * 32 + quad * 8;

    for (int s = ks; s < ke; ++s) {
        bf16x8 ah = *(const bf16x8*)(Ah + aoff);
        bf16x8 al = *(const bf16x8*)(Al + aoff);
        bf16x8 wh = *(const bf16x8*)(Wh + woff);
        bf16x8 wl = *(const bf16x8*)(Wl + woff);
        aoff += 32; woff += 32;
        acc = __builtin_amdgcn_mfma_f32_16x16x32_bf16(ah, wh, acc, 0, 0, 0);
        acc = __builtin_amdgcn_mfma_f32_16x16x32_bf16(al, wh, acc, 0, 0, 0);
        acc = __builtin_amdgcn_mfma_f32_16x16x32_bf16(ah, wl, acc, 0, 0, 0);
    }

    if (wave > 0) {
        #pragma unroll
        for (int r = 0; r < 4; ++r) red[(r * 3 + (wave - 1)) * 64 + lane] = acc[r];
    }
    __syncthreads();
    if (wave == 0) {
        const int col = n0 + l15;
        const float bc = bias[col];
        #pragma unroll
        for (int r = 0; r < 4; ++r) {
            const int m = m0 + quad * 4 + r;
            float v = acc[r] + red[(r * 3 + 0) * 64 + lane] + red[(r * 3 + 1) * 64 + lane]
                    + red[(r * 3 + 2) * 64 + lane] + bc;
            C[(size_t)m * ldc + col] = v;
        }
    }
}

// ---------------------------------------------------------------------------
// DNC memory step for one batch element; 256 threads enter, work mostly on
// the first 64; all __syncthreads unconditional.
// ---------------------------------------------------------------------------
__device__ void mem_step_dev(int b, int tid, float* S, int* phi,
    const float* iface, float* mem, float* link, float* prec, float* rw,
    float* ww, float* usage, __bf16* dsth, __bf16* dstl, int dstst)
{
    float* sif = S;            // 163
    float* modes = S + 164;    // 12
    float* us = S + 176;       // 16
    float* wwold = S + 192;    // 16
    float* wwnew = S + 208;    // 16
    float* precold = S + 224;  // 16
    float* rwold = S + 240;    // 64
    float* rwnewS = S + 304;   // 64
    float* lnk = S + 368;      // 256
    float* memS = S + 624;     // 320
    float* wcw = S + 944;      // 16
    float* allocS = S + 960;   // 16
    float* rcw = S + 976;      // 64
    float* uu = S + 1040;      // 16
    float* sumww = S + 1056;   // 1

    const float* ifr = iface + (size_t)b * IFP_;
    for (int i = tid; i < IFACE_; i += 256) {
        float v = ifr[i];
        float r;
        if (i < 80)        r = tanhf(v);
        else if (i < 84)   r = softplusf_(v);
        else if (i < 104)  r = tanhf(v);
        else if (i < 105)  r = softplusf_(v);
        else if (i < 125)  r = sigmoidf_(v);
        else if (i < 145)  r = tanhf(v);
        else if (i < 149)  r = sigmoidf_(v);
        else if (i < 151)  r = sigmoidf_(v);
        else               r = v;
        sif[i] = r;
    }
    if (tid < M_) {
        us[tid]      = usage[(size_t)b * M_ + tid];
        wwold[tid]   = ww[(size_t)b * M_ + tid];
        precold[tid] = prec[(size_t)b * M_ + tid];
    }
    if (tid < R_ * M_) rwold[tid] = rw[(size_t)b * R_ * M_ + tid];
    if (tid < M_ * M_) lnk[tid] = link[(size_t)b * M_ * M_ + tid];
    for (int i = tid; i < M_ * WC_; i += 256) memS[i] = mem[(size_t)b * M_ * WC_ + i];
    __syncthreads();

    if (tid < R_) {
        float a0 = sif[151 + tid * 3], a1 = sif[152 + tid * 3], a2 = sif[153 + tid * 3];
        float mx = fmaxf(a0, fmaxf(a1, a2));
        float e0 = expf(a0 - mx), e1 = expf(a1 - mx), e2 = expf(a2 - mx);
        float s = e0 + e1 + e2;
        modes[tid * 3 + 0] = e0 / s; modes[tid * 3 + 1] = e1 / s; modes[tid * 3 + 2] = e2 / s;
    }
    if (tid < M_) {
        float u = us[tid];
        u = u + (1.f - u) * wwold[tid];
        float psi = 1.f;
        #pragma unroll
        for (int r = 0; r < R_; ++r) psi *= (1.f - sif[145 + r] * rwold[r * 16 + tid]);
        u *= psi;
        us[tid] = u;
    }
    if (tid < M_) {
        float kn2 = 0.f, mn2 = 0.f, dot = 0.f;
        #pragma unroll
        for (int w = 0; w < WC_; ++w) {
            float kv = sif[84 + w], mv = memS[tid * WC_ + w];
            kn2 += kv * kv; mn2 += mv * mv; dot += kv * mv;
        }
        float c = dot / ((sqrtf(kn2) + EPS_) * (sqrtf(mn2) + EPS_));
        wcw[tid] = c * sif[104];
    }
    __syncthreads();

    if (tid == 0) {
        float mx = -1e30f;
        for (int m = 0; m < M_; ++m) mx = fmaxf(mx, wcw[m]);
        float s = 0.f;
        for (int m = 0; m < M_; ++m) { wcw[m] = expf(wcw[m] - mx); s += wcw[m]; }
        for (int m = 0; m < M_; ++m) wcw[m] /= s;
        for (int m = 0; m < M_; ++m) { uu[m] = DELTA_ + (1.f - DELTA_) * us[m]; phi[m] = m; }
        for (int j = 1; j < M_; ++j) {
            float key = uu[j]; int kp = phi[j];
            int i2 = j - 1;
            while (i2 >= 0 && uu[i2] > key) { uu[i2 + 1] = uu[i2]; phi[i2 + 1] = phi[i2]; --i2; }
            uu[i2 + 1] = key; phi[i2 + 1] = kp;
        }
        float prod = 1.f;
        for (int j = 0; j < M_; ++j) {
            float sa = (1.f - uu[j]) * prod;
            prod *= uu[j];
            allocS[phi[j]] = sa;
        }
    }
    __syncthreads();

    if (tid < M_) {
        wwnew[tid] = sif[150] * (sif[149] * allocS[tid] + (1.f - sif[149]) * wcw[tid]);
    }
    __syncthreads();

    if (tid == 0) {
        float s = 0.f;
        for (int m = 0; m < M_; ++m) s += wwnew[m];
        sumww[0] = s;
    }
    for (int i = tid; i < M_ * WC_; i += 256) {
        int m = i / WC_, w = i - m * WC_;
        float nm = memS[i] * (1.f - wwnew[m] * sif[105 + w]) + wwnew[m] * sif[125 + w];
        memS[i] = nm;
        mem[(size_t)b * M_ * WC_ + i] = nm;
    }
    __syncthreads();

    if (tid < M_ * M_) {
        int i = tid >> 4, j = tid & 15;
        float v = (1.f - wwnew[i] - wwnew[j]) * lnk[tid] + wwnew[i] * precold[j];
        if (i == j) v = 0.f;
        lnk[tid] = v;
        link[(size_t)b * M_ * M_ + tid] = v;
    }
    if (tid < M_) {
        prec[(size_t)b * M_ + tid] = (1.f - sumww[0]) * precold[tid] + wwnew[tid];
        usage[(size_t)b * M_ + tid] = us[tid];
        ww[(size_t)b * M_ + tid] = wwnew[tid];
    }
    __syncthreads();

    if (tid < 64) {
        int r = tid >> 4, m = tid & 15;
        float kn2 = 0.f, mn2 = 0.f, dot = 0.f;
        #pragma unroll
        for (int w = 0; w < WC_; ++w) {
            float kv = sif[r * WC_ + w], mv = memS[m * WC_ + w];
            kn2 += kv * kv; mn2 += mv * mv; dot += kv * mv;
        }
        float c = dot / ((sqrtf(kn2) + EPS_) * (sqrtf(mn2) + EPS_));
        rcw[r * 16 + m] = c * sif[80 + r];
    }
    __syncthreads();
    if (tid < R_) {
        float mx = -1e30f;
        for (int m = 0; m < M_; ++m) mx = fmaxf(mx, rcw[tid * 16 + m]);
        float s = 0.f;
        for (int m = 0; m < M_; ++m) { rcw[tid * 16 + m] = expf(rcw[tid * 16 + m] - mx); s += rcw[tid * 16 + m]; }
        for (int m = 0; m < M_; ++m) rcw[tid * 16 + m] /= s;
    }
    __syncthreads();

    if (tid < 64) {
        int r = tid >> 4, m = tid & 15;
        float fwd = 0.f, bwd = 0.f;
        #pragma unroll
        for (int j = 0; j < M_; ++j) fwd += lnk[m * 16 + j] * rwold[r * 16 + j];
        #pragma unroll
        for (int i = 0; i < M_; ++i) bwd += rwold[r * 16 + i] * lnk[i * 16 + m];
        float v = modes[r * 3 + 0] * bwd + modes[r * 3 + 1] * fwd + modes[r * 3 + 2] * rcw[r * 16 + m];
        rwnewS[r * 16 + m] = v;
        rw[(size_t)b * R_ * M_ + tid] = v;
    }
    __syncthreads();

    if (tid < RW_) {
        int r = tid / WC_, w = tid - r * WC_;
        float s = 0.f;
        #pragma unroll
        for (int m = 0; m < M_; ++m) s += rwnewS[r * 16 + m] * memS[m * WC_ + w];
        split2(s, &dsth[(size_t)b * dstst + IN_ + tid], &dstl[(size_t)b * dstst + IN_ + tid]);
    }
}

// ---------------------------------------------------------------------------
// The whole forward pass: one cooperative kernel, grid syncs between stages.
// ---------------------------------------------------------------------------
__global__ void __launch_bounds__(256, 1) dnc_kernel(Args a)
{
    cg::grid_group grid = cg::this_grid();
    const int blk = blockIdx.x;
    const int tid = threadIdx.x;
    const int gtid = blk * 256 + tid;

    __shared__ float smem[3072];
    __shared__ int phiS[16];

    // ---- stage 0: weight split/convert + inp(t=0) ----
    for (int l = 0; l < 2; ++l) {
        const float* sih = a.W_ih0 + (size_t)l * 2048 * NNIN_;
        const float* shh = a.W_hh0 + (size_t)l * 2048 * H_;
        for (int i = gtid; i < 2048 * K1P_; i += NT_) {
            int n = i / K1P_, k = i - n * K1P_;
            float v = (k < NNIN_) ? sih[(size_t)n * NNIN_ + k]
                    : (k < NNIN_ + H_ ? shh[(size_t)n * H_ + (k - NNIN_)] : 0.f);
            split2(v, &a.w1h[l][i], &a.w1l[l][i]);
        }
        const float* sih1 = a.W_ih1 + (size_t)l * 2048 * H_;
        const float* shh1 = a.W_hh1 + (size_t)l * 2048 * H_;
        for (int i = gtid; i < 2048 * K2P_; i += NT_) {
            int n = i >> 10, k = i & 1023;
            float v = (k < 512) ? sih1[(size_t)n * H_ + k] : shh1[(size_t)n * H_ + (k - 512)];
            split2(v, &a.w2h[l][i], &a.w2l[l][i]);
        }
        const float* sif2 = a.W_iface + (size_t)l * IFACE_ * H_;
        for (int i = gtid; i < IFP_ * H_; i += NT_) {
            int n = i >> 9, k = i & 511;
            float v = (n < IFACE_) ? sif2[(size_t)n * H_ + k] : 0.f;
            split2(v, &a.wifh[l][i], &a.wifl[l][i]);
        }
    }
    for (int i = gtid; i < 512 * KOP_; i += NT_) {
        int n = i / KOP_, k = i - n * KOP_;
        float v = (k < NNIN_) ? a.W_out[(size_t)n * NNIN_ + k] : 0.f;
        split2(v, &a.wouth[i], &a.woutl[i]);
    }
    if (gtid < 2 * IFP_) {
        int l = gtid / IFP_, k = gtid - l * IFP_;
        a.biasif[gtid] = (k < IFACE_) ? a.b_iface[l * IFACE_ + k] : 0.f;
    }
    { // inp(0): one element per thread
        int b = gtid >> 9, j = gtid & 511;
        float v = a.x[((size_t)b * T_ + 0) * IN_ + j];
        split2(v, &a.a1h[0][0][b * K1P_ + j], &a.a1l[0][0][b * K1P_ + j]);
    }
    grid.sync();

    const int jt = blk & 31, mt = blk >> 5;

    for (int t = 0; t < T_; ++t) {
        const int par = t & 1;
        for (int l = 0; l < 2; ++l) {
            float* c0 = a.cbuf + (size_t)(l * 2 + 0) * B_ * H_;
            float* c1 = a.cbuf + (size_t)(l * 2 + 1) * B_ * H_;
            __bf16 *clh, *cll; int clst;
            if (l == 0) { clh = a.a1h[1][par]; cll = a.a1l[1][par]; clst = K1P_; }
            else        { clh = a.yinh;        cll = a.yinl;        clst = KOP_; }

            // s1: lstm cell A (reads a1[l][par], writes h0 -> a2[l][par][0:512]
            //     and a1[l][par^1][592:1104])
            gemm_lstm_tile(tid, jt, mt, smem,
                a.a1h[l][par], a.a1l[l][par], K1P_, a.w1h[l], a.w1l[l], K1P_ / 32,
                a.b_ih0 + l * 2048, a.b_hh0 + l * 2048, c0,
                a.a2h[l][par], a.a2l[l][par], K2P_, 0,
                a.a1h[l][par ^ 1], a.a1l[l][par ^ 1], K1P_, NNIN_, 0);
            grid.sync();

            // s2: lstm cell B (reads a2[l][par], writes h1 -> a2[l][par^1][512:1024],
            //     clip(h1) -> next-consumer buffer)
            gemm_lstm_tile(tid, jt, mt, smem,
                a.a2h[l][par], a.a2l[l][par], K2P_, a.w2h[l], a.w2l[l], K2P_ / 32,
                a.b_ih1 + l * 2048, a.b_hh1 + l * 2048, c1,
                a.a2h[l][par ^ 1], a.a2l[l][par ^ 1], K2P_, H_,
                clh, cll, clst, 0, 1);
            grid.sync();

            // s3: iface GEMM on blocks 0..95; (l==0 only) out GEMM for t-1 on 96..255
            if (blk < 96) {
                gemm_plain_tile(tid, blk % 12, blk / 12, smem,
                    clh, cll, clst, a.wifh[l], a.wifl[l], H_, H_ / 32,
                    a.biasif + l * IFP_, a.ifacev, IFP_);
            } else if (l == 0 && t > 0) {
                for (int tile = blk - 96; tile < 256; tile += 160) {
                    gemm_plain_tile(tid, tile & 31, tile >> 5, smem,
                        a.yinh, a.yinl, KOP_, a.wouth, a.woutl, KOP_, KOP_ / 32,
                        a.b_out, a.out + (size_t)(t - 1) * IN_, T_ * IN_);
                    __syncthreads();
                }
            }
            grid.sync();

            // s4: mem step on blocks 0..127; (l==0 only) inp(t+1) on 128..255
            if (blk < B_) {
                mem_step_dev(blk, tid, smem, phiS, a.ifacev,
                    a.memv + (size_t)l * B_ * M_ * WC_,
                    a.linkv + (size_t)l * B_ * M_ * M_,
                    a.precv + (size_t)l * B_ * M_,
                    a.rwv + (size_t)l * B_ * R_ * M_,
                    a.wwv + (size_t)l * B_ * M_,
                    a.usagev + (size_t)l * B_ * M_,
                    clh, cll, clst);
            } else if (l == 0 && t + 1 < T_) {
                for (int i = (blk - 128) * 256 + tid; i < B_ * IN_; i += 128 * 256) {
                    int b = i >> 9, j = i & 511;
                    float v = a.x[((size_t)b * T_ + (t + 1)) * IN_ + j];
                    split2(v, &a.a1h[0][par ^ 1][b * K1P_ + j], &a.a1l[0][par ^ 1][b * K1P_ + j]);
                }
            }
            grid.sync();
        }
    }

    // final out GEMM (t = T-1), all blocks
    gemm_plain_tile(tid, jt, mt, smem,
        a.yinh, a.yinl, KOP_, a.wouth, a.woutl, KOP_, KOP_ / 32,
        a.b_out, a.out + (size_t)(T_ - 1) * IN_, T_ * IN_);
}

// ---------------------------------------------------------------------------
extern "C" void kernel_launch(void* const* d_in, const int* in_sizes, int n_in,
                              void* d_out, int out_size, void* d_ws, size_t ws_size,
                              hipStream_t stream)
{
    Args a;
    a.x       = (const float*)d_in[0];
    a.W_ih0   = (const float*)d_in[1];
    a.W_hh0   = (const float*)d_in[2];
    a.b_ih0   = (const float*)d_in[3];
    a.b_hh0   = (const float*)d_in[4];
    a.W_ih1   = (const float*)d_in[5];
    a.W_hh1   = (const float*)d_in[6];
    a.b_ih1   = (const float*)d_in[7];
    a.b_hh1   = (const float*)d_in[8];
    a.W_iface = (const float*)d_in[9];
    a.b_iface = (const float*)d_in[10];
    a.W_out   = (const float*)d_in[11];
    a.b_out   = (const float*)d_in[12];
    a.out     = (float*)d_out;

    char* p = (char*)d_ws;
    auto alloc = [&](size_t bytes) { char* r = p; p += (bytes + 255) & ~(size_t)255; return r; };

    // ---- zero zone ----
    char* zstart = p;
    for (int l = 0; l < 2; ++l)
        for (int q = 0; q < 2; ++q) {
            a.a1h[l][q] = (__bf16*)alloc(B_ * K1P_ * 2);
            a.a1l[l][q] = (__bf16*)alloc(B_ * K1P_ * 2);
        }
    for (int l = 0; l < 2; ++l)
        for (int q = 0; q < 2; ++q) {
            a.a2h[l][q] = (__bf16*)alloc(B_ * K2P_ * 2);
            a.a2l[l][q] = (__bf16*)alloc(B_ * K2P_ * 2);
        }
    a.yinh = (__bf16*)alloc(B_ * KOP_ * 2);
    a.yinl = (__bf16*)alloc(B_ * KOP_ * 2);
    a.cbuf   = (float*)alloc(4ull * B_ * H_ * 4);
    a.memv   = (float*)alloc(2ull * B_ * M_ * WC_ * 4);
    a.linkv  = (float*)alloc(2ull * B_ * M_ * M_ * 4);
    a.precv  = (float*)alloc(2ull * B_ * M_ * 4);
    a.rwv    = (float*)alloc(2ull * B_ * R_ * M_ * 4);
    a.wwv    = (float*)alloc(2ull * B_ * M_ * 4);
    a.usagev = (float*)alloc(2ull * B_ * M_ * 4);
    size_t zbytes = (size_t)(p - zstart);

    // ---- non-zero scratch ----
    a.ifacev = (float*)alloc(B_ * IFP_ * 4);
    for (int l = 0; l < 2; ++l) {
        a.w1h[l] = (__bf16*)alloc(2048ull * K1P_ * 2);
        a.w1l[l] = (__bf16*)alloc(2048ull * K1P_ * 2);
    }
    for (int l = 0; l < 2; ++l) {
        a.w2h[l] = (__bf16*)alloc(2048ull * K2P_ * 2);
        a.w2l[l] = (__bf16*)alloc(2048ull * K2P_ * 2);
    }
    for (int l = 0; l < 2; ++l) {
        a.wifh[l] = (__bf16*)alloc((size_t)IFP_ * H_ * 2);
        a.wifl[l] = (__bf16*)alloc((size_t)IFP_ * H_ * 2);
    }
    a.wouth = (__bf16*)alloc(512ull * KOP_ * 2);
    a.woutl = (__bf16*)alloc(512ull * KOP_ * 2);
    a.biasif = (float*)alloc(2ull * IFP_ * 4);

    hipMemsetAsync(zstart, 0, zbytes, stream);

    void* kparams[] = { (void*)&a };
    hipLaunchCooperativeKernel((const void*)dnc_kernel, dim3(256), dim3(256),
                               kparams, 0, stream);
}

// Round 8
// 3530.434 us; speedup vs baseline: 2.6521x; 2.6521x over previous
//
#include <hip/hip_runtime.h>
#include <hip/hip_bf16.h>
#include <math.h>

#define B_ 128
#define T_ 32
#define IN_ 512
#define H_ 512
#define M_ 16
#define WC_ 20
#define R_ 4
#define RW_ 80
#define NNIN_ 592
#define IFACE_ 163
#define K1P_ 1120
#define K2P_ 1024
#define KOP_ 608
#define CLIP_ 20.0f
#define EPS_ 1e-6f
#define DELTA_ 5e-6f

typedef __bf16 bf16x8 __attribute__((ext_vector_type(8)));
typedef float f32x4 __attribute__((ext_vector_type(4)));

__device__ __forceinline__ float sigmoidf_(float x) { return 1.0f / (1.0f + expf(-x)); }
__device__ __forceinline__ float softplusf_(float x) {
    return fmaxf(x, 0.0f) + log1pf(expf(-fabsf(x)));
}
__device__ __forceinline__ void split2(float v, __bf16* hp, __bf16* lp) {
    __bf16 h = (__bf16)v;
    *hp = h;
    *lp = (__bf16)(v - (float)h);
}

// ---------------------------------------------------------------------------
// Weight conversion: dst[n][k] (k<K1: src1, k<K1+K2: src2, else 0) -> hi/lo
// ---------------------------------------------------------------------------
__global__ __launch_bounds__(256) void conv_split(
    const float* __restrict__ s1, int K1, const float* __restrict__ s2, int K2,
    int Nsrc, __bf16* __restrict__ hi, __bf16* __restrict__ lo, int Kd)
{
    int k = blockIdx.x * 256 + threadIdx.x;
    int n = blockIdx.y;
    if (k >= Kd) return;
    float v = 0.f;
    if (n < Nsrc) {
        if (k < K1) v = s1[(size_t)n * K1 + k];
        else if (k < K1 + K2) v = s2[(size_t)n * K2 + (k - K1)];
    }
    __bf16 h = (__bf16)v;
    hi[(size_t)n * Kd + k] = h;
    lo[(size_t)n * Kd + k] = (__bf16)(v - (float)h);
}

// x_t=0 -> a1[0][0] cols [0,512)
__global__ __launch_bounds__(256) void build_inp(const float* __restrict__ x,
                                                 __bf16* __restrict__ a1h,
                                                 __bf16* __restrict__ a1l)
{
    int idx = blockIdx.x * 256 + threadIdx.x;
    if (idx >= B_ * IN_) return;
    int b = idx >> 9, j = idx & 511;
    float v = x[(size_t)b * T_ * IN_ + j];
    split2(v, &a1h[b * K1P_ + j], &a1l[b * K1P_ + j]);
}

// ---------------------------------------------------------------------------
// Fused LSTM GEMM+pointwise: 16x16x32 MFMA, block = 16x16 (batch x hidden)
// tile of ALL 4 gates; 4 waves split K; wave0 does LSTM epilogue.
// ---------------------------------------------------------------------------
__global__ __launch_bounds__(256) void gemm_lstm16(
    const __bf16* __restrict__ Ah, const __bf16* __restrict__ Al, const int KS,
    const __bf16* __restrict__ Wh, const __bf16* __restrict__ Wl,
    const int nsteps,
    const float* __restrict__ b1, const float* __restrict__ b2,
    float* __restrict__ cst,
    __bf16* __restrict__ d1h, __bf16* __restrict__ d1l, int st1, int off1,
    __bf16* __restrict__ d2h, __bf16* __restrict__ d2l, int st2, int off2,
    int clip2)
{
    const int tid = threadIdx.x;
    const int wave = tid >> 6, lane = tid & 63;
    const int l15 = lane & 15, quad = lane >> 4;
    const int j0 = blockIdx.x * 16;
    const int m0 = blockIdx.y * 16;

    f32x4 acc[4];
    #pragma unroll
    for (int g = 0; g < 4; ++g)
        #pragma unroll
        for (int i = 0; i < 4; ++i) acc[g][i] = 0.f;

    const int ks = (wave * nsteps) >> 2;
    const int ke = ((wave + 1) * nsteps) >> 2;

    size_t aoff = (size_t)(m0 + l15) * KS + ks * 32 + quad * 8;
    size_t woff[4];
    #pragma unroll
    for (int g = 0; g < 4; ++g)
        woff[g] = (size_t)(g * 512 + j0 + l15) * KS + ks * 32 + quad * 8;

    for (int s = ks; s < ke; ++s) {
        bf16x8 ah = *(const bf16x8*)(Ah + aoff);
        bf16x8 al = *(const bf16x8*)(Al + aoff);
        aoff += 32;
        #pragma unroll
        for (int g = 0; g < 4; ++g) {
            bf16x8 wh = *(const bf16x8*)(Wh + woff[g]);
            bf16x8 wl = *(const bf16x8*)(Wl + woff[g]);
            woff[g] += 32;
            acc[g] = __builtin_amdgcn_mfma_f32_16x16x32_bf16(ah, wh, acc[g], 0, 0, 0);
            acc[g] = __builtin_amdgcn_mfma_f32_16x16x32_bf16(al, wh, acc[g], 0, 0, 0);
            acc[g] = __builtin_amdgcn_mfma_f32_16x16x32_bf16(ah, wl, acc[g], 0, 0, 0);
        }
    }

    __shared__ float red[16][3][64];
    if (wave > 0) {
        #pragma unroll
        for (int g = 0; g < 4; ++g)
            #pragma unroll
            for (int r = 0; r < 4; ++r)
                red[g * 4 + r][wave - 1][lane] = acc[g][r];
    }
    __syncthreads();
    if (wave == 0) {
        const int col = j0 + l15;
        float bg[4];
        #pragma unroll
        for (int g = 0; g < 4; ++g) bg[g] = b1[g * 512 + col] + b2[g * 512 + col];
        #pragma unroll
        for (int r = 0; r < 4; ++r) {
            const int m = m0 + quad * 4 + r;
            float gv[4];
            #pragma unroll
            for (int g = 0; g < 4; ++g) {
                int i = g * 4 + r;
                gv[g] = acc[g][r] + red[i][0][lane] + red[i][1][lane] + red[i][2][lane] + bg[g];
            }
            float cold = cst[m * H_ + col];
            float cn = sigmoidf_(gv[1]) * cold + sigmoidf_(gv[0]) * tanhf(gv[2]);
            cst[m * H_ + col] = cn;
            float h = sigmoidf_(gv[3]) * tanhf(cn);
            split2(h, &d1h[(size_t)m * st1 + off1 + col], &d1l[(size_t)m * st1 + off1 + col]);
            float h2 = clip2 ? fminf(fmaxf(h, -CLIP_), CLIP_) : h;
            split2(h2, &d2h[(size_t)m * st2 + off2 + col], &d2l[(size_t)m * st2 + off2 + col]);
        }
    }
}

// ---------------------------------------------------------------------------
// Plain GEMM tile (out projection): 16x16, 4 waves split K, fp32 + bias out
// ---------------------------------------------------------------------------
__device__ __forceinline__ void gemm_plain_tile(
    int tid, int nt, int mt, float* red,
    const __bf16* Ah, const __bf16* Al, int AS,
    const __bf16* Wh, const __bf16* Wl, int WS,
    int nsteps, const float* bias, float* C, int ldc)
{
    const int wave = tid >> 6, lane = tid & 63;
    const int l15 = lane & 15, quad = lane >> 4;
    const int n0 = nt * 16, m0 = mt * 16;

    f32x4 acc;
    #pragma unroll
    for (int i = 0; i < 4; ++i) acc[i] = 0.f;

    const int ks = (wave * nsteps) >> 2;
    const int ke = ((wave + 1) * nsteps) >> 2;

    size_t aoff = (size_t)(m0 + l15) * AS + ks * 32 + quad * 8;
    size_t woff = (size_t)(n0 + l15) * WS + ks * 32 + quad * 8;

    for (int s = ks; s < ke; ++s) {
        bf16x8 ah = *(const bf16x8*)(Ah + aoff);
        bf16x8 al = *(const bf16x8*)(Al + aoff);
        bf16x8 wh = *(const bf16x8*)(Wh + woff);
        bf16x8 wl = *(const bf16x8*)(Wl + woff);
        aoff += 32; woff += 32;
        acc = __builtin_amdgcn_mfma_f32_16x16x32_bf16(ah, wh, acc, 0, 0, 0);
        acc = __builtin_amdgcn_mfma_f32_16x16x32_bf16(al, wh, acc, 0, 0, 0);
        acc = __builtin_amdgcn_mfma_f32_16x16x32_bf16(ah, wl, acc, 0, 0, 0);
    }

    if (wave > 0) {
        #pragma unroll
        for (int r = 0; r < 4; ++r) red[(r * 3 + (wave - 1)) * 64 + lane] = acc[r];
    }
    __syncthreads();
    if (wave == 0) {
        const int col = n0 + l15;
        const float bc = bias[col];
        #pragma unroll
        for (int r = 0; r < 4; ++r) {
            const int m = m0 + quad * 4 + r;
            float v = acc[r] + red[(r * 3 + 0) * 64 + lane] + red[(r * 3 + 1) * 64 + lane]
                    + red[(r * 3 + 2) * 64 + lane] + bc;
            C[(size_t)m * ldc + col] = v;
        }
    }
}

__global__ __launch_bounds__(256) void gemm_plain16(
    const __bf16* __restrict__ Ah, const __bf16* __restrict__ Al, const int AS,
    const __bf16* __restrict__ Wh, const __bf16* __restrict__ Wl, const int WS,
    const int nsteps, const float* __restrict__ bias,
    float* __restrict__ C, const int ldc)
{
    __shared__ float red[12 * 64];
    gemm_plain_tile(threadIdx.x, blockIdx.x, blockIdx.y, red,
                    Ah, Al, AS, Wh, Wl, WS, nsteps, bias, C, ldc);
}

// ---------------------------------------------------------------------------
// DNC memory-step core (one block per batch element, 256 threads). S holds
// the TRANSFORMED iface vector in S[0..162] on entry.
// ---------------------------------------------------------------------------
__device__ void mem_core(int b, int tid, float* S, int* phi,
    float* mem, float* link, float* prec, float* rw,
    float* ww, float* usage, __bf16* rvh, __bf16* rvl, int rvst)
{
    float* sif = S;            // 163
    float* modes = S + 164;    // 12
    float* us = S + 176;       // 16
    float* wwold = S + 192;    // 16
    float* wwnew = S + 208;    // 16
    float* precold = S + 224;  // 16
    float* rwold = S + 240;    // 64
    float* rwnewS = S + 304;   // 64
    float* lnk = S + 368;      // 256
    float* memS = S + 624;     // 320
    float* wcw = S + 944;      // 16
    float* allocS = S + 960;   // 16
    float* rcw = S + 976;      // 64
    float* uu = S + 1040;      // 16
    float* sumww = S + 1056;   // 1

    if (tid < M_) {
        us[tid]      = usage[(size_t)b * M_ + tid];
        wwold[tid]   = ww[(size_t)b * M_ + tid];
        precold[tid] = prec[(size_t)b * M_ + tid];
    }
    if (tid < R_ * M_) rwold[tid] = rw[(size_t)b * R_ * M_ + tid];
    if (tid < M_ * M_) lnk[tid] = link[(size_t)b * M_ * M_ + tid];
    for (int i = tid; i < M_ * WC_; i += 256) memS[i] = mem[(size_t)b * M_ * WC_ + i];
    __syncthreads();

    if (tid < R_) {
        float a0 = sif[151 + tid * 3], a1 = sif[152 + tid * 3], a2 = sif[153 + tid * 3];
        float mx = fmaxf(a0, fmaxf(a1, a2));
        float e0 = expf(a0 - mx), e1 = expf(a1 - mx), e2 = expf(a2 - mx);
        float s = e0 + e1 + e2;
        modes[tid * 3 + 0] = e0 / s; modes[tid * 3 + 1] = e1 / s; modes[tid * 3 + 2] = e2 / s;
    }
    if (tid < M_) {
        float u = us[tid];
        u = u + (1.f - u) * wwold[tid];
        float psi = 1.f;
        #pragma unroll
        for (int r = 0; r < R_; ++r) psi *= (1.f - sif[145 + r] * rwold[r * 16 + tid]);
        u *= psi;
        us[tid] = u;
    }
    if (tid < M_) {
        float kn2 = 0.f, mn2 = 0.f, dot = 0.f;
        #pragma unroll
        for (int w = 0; w < WC_; ++w) {
            float kv = sif[84 + w], mv = memS[tid * WC_ + w];
            kn2 += kv * kv; mn2 += mv * mv; dot += kv * mv;
        }
        float c = dot / ((sqrtf(kn2) + EPS_) * (sqrtf(mn2) + EPS_));
        wcw[tid] = c * sif[104];
    }
    __syncthreads();

    if (tid == 0) {
        float mx = -1e30f;
        for (int m = 0; m < M_; ++m) mx = fmaxf(mx, wcw[m]);
        float s = 0.f;
        for (int m = 0; m < M_; ++m) { wcw[m] = expf(wcw[m] - mx); s += wcw[m]; }
        for (int m = 0; m < M_; ++m) wcw[m] /= s;
        for (int m = 0; m < M_; ++m) { uu[m] = DELTA_ + (1.f - DELTA_) * us[m]; phi[m] = m; }
        for (int j = 1; j < M_; ++j) {
            float key = uu[j]; int kp = phi[j];
            int i2 = j - 1;
            while (i2 >= 0 && uu[i2] > key) { uu[i2 + 1] = uu[i2]; phi[i2 + 1] = phi[i2]; --i2; }
            uu[i2 + 1] = key; phi[i2 + 1] = kp;
        }
        float prod = 1.f;
        for (int j = 0; j < M_; ++j) {
            float sa = (1.f - uu[j]) * prod;
            prod *= uu[j];
            allocS[phi[j]] = sa;
        }
    }
    __syncthreads();

    if (tid < M_) {
        wwnew[tid] = sif[150] * (sif[149] * allocS[tid] + (1.f - sif[149]) * wcw[tid]);
    }
    __syncthreads();

    if (tid == 0) {
        float s = 0.f;
        for (int m = 0; m < M_; ++m) s += wwnew[m];
        sumww[0] = s;
    }
    for (int i = tid; i < M_ * WC_; i += 256) {
        int m = i / WC_, w = i - m * WC_;
        float nm = memS[i] * (1.f - wwnew[m] * sif[105 + w]) + wwnew[m] * sif[125 + w];
        memS[i] = nm;
        mem[(size_t)b * M_ * WC_ + i] = nm;
    }
    __syncthreads();

    if (tid < M_ * M_) {
        int i = tid >> 4, j = tid & 15;
        float v = (1.f - wwnew[i] - wwnew[j]) * lnk[tid] + wwnew[i] * precold[j];
        if (i == j) v = 0.f;
        lnk[tid] = v;
        link[(size_t)b * M_ * M_ + tid] = v;
    }
    if (tid < M_) {
        prec[(size_t)b * M_ + tid] = (1.f - sumww[0]) * precold[tid] + wwnew[tid];
        usage[(size_t)b * M_ + tid] = us[tid];
        ww[(size_t)b * M_ + tid] = wwnew[tid];
    }
    __syncthreads();

    if (tid < 64) {
        int r = tid >> 4, m = tid & 15;
        float kn2 = 0.f, mn2 = 0.f, dot = 0.f;
        #pragma unroll
        for (int w = 0; w < WC_; ++w) {
            float kv = sif[r * WC_ + w], mv = memS[m * WC_ + w];
            kn2 += kv * kv; mn2 += mv * mv; dot += kv * mv;
        }
        float c = dot / ((sqrtf(kn2) + EPS_) * (sqrtf(mn2) + EPS_));
        rcw[r * 16 + m] = c * sif[80 + r];
    }
    __syncthreads();
    if (tid < R_) {
        float mx = -1e30f;
        for (int m = 0; m < M_; ++m) mx = fmaxf(mx, rcw[tid * 16 + m]);
        float s = 0.f;
        for (int m = 0; m < M_; ++m) { rcw[tid * 16 + m] = expf(rcw[tid * 16 + m] - mx); s += rcw[tid * 16 + m]; }
        for (int m = 0; m < M_; ++m) rcw[tid * 16 + m] /= s;
    }
    __syncthreads();

    if (tid < 64) {
        int r = tid >> 4, m = tid & 15;
        float fwd = 0.f, bwd = 0.f;
        #pragma unroll
        for (int j = 0; j < M_; ++j) fwd += lnk[m * 16 + j] * rwold[r * 16 + j];
        #pragma unroll
        for (int i = 0; i < M_; ++i) bwd += rwold[r * 16 + i] * lnk[i * 16 + m];
        float v = modes[r * 3 + 0] * bwd + modes[r * 3 + 1] * fwd + modes[r * 3 + 2] * rcw[r * 16 + m];
        rwnewS[r * 16 + m] = v;
        rw[(size_t)b * R_ * M_ + tid] = v;
    }
    __syncthreads();

    if (tid < RW_) {
        int r = tid / WC_, w = tid - r * WC_;
        float s = 0.f;
        #pragma unroll
        for (int m = 0; m < M_; ++m) s += rwnewS[r * 16 + m] * memS[m * WC_ + w];
        split2(s, &rvh[(size_t)b * rvst + IN_ + tid], &rvl[(size_t)b * rvst + IN_ + tid]);
    }
}

// ---------------------------------------------------------------------------
// Fused iface-GEMV + mem-step (blocks 0..127, one batch row each); blocks
// 128..255 run the y(t-1) output GEMM (do_out) and/or x(t+1) prefetch (do_x).
// ---------------------------------------------------------------------------
__global__ __launch_bounds__(256) void ifmem(
    const __bf16* __restrict__ och, const __bf16* __restrict__ ocl, int ost,
    const float* __restrict__ Wif, const float* __restrict__ bif,
    float* mem, float* link, float* prec, float* rw, float* ww, float* usage,
    __bf16* rvh, __bf16* rvl,
    int do_out, const __bf16* __restrict__ yh, const __bf16* __restrict__ yl,
    const __bf16* __restrict__ woh, const __bf16* __restrict__ wol,
    const float* __restrict__ bout, float* outp,
    int do_x, const float* __restrict__ x, int tnext,
    __bf16* xdh, __bf16* xdl)
{
    __shared__ float smem[1728];
    __shared__ int phiS[16];
    const int blk = blockIdx.x, tid = threadIdx.x;

    if (blk < B_) {
        float* af = smem;        // 512: reconstructed out vector
        float* S  = smem + 512;  // 1057: mem-step workspace (sif at S[0])
        const int b = blk;
        for (int i = tid; i < 512; i += 256)
            af[i] = (float)och[(size_t)b * ost + i] + (float)ocl[(size_t)b * ost + i];
        __syncthreads();
        if (tid < IFACE_) {
            const float* wr = Wif + (size_t)tid * 512;
            float acc = 0.f;
            for (int k = 0; k < 512; k += 4)
                acc += af[k] * wr[k] + af[k + 1] * wr[k + 1]
                     + af[k + 2] * wr[k + 2] + af[k + 3] * wr[k + 3];
            float v = acc + bif[tid];
            int i = tid;
            float r;
            if (i < 80)        r = tanhf(v);
            else if (i < 84)   r = softplusf_(v);
            else if (i < 104)  r = tanhf(v);
            else if (i < 105)  r = softplusf_(v);
            else if (i < 125)  r = sigmoidf_(v);
            else if (i < 145)  r = tanhf(v);
            else if (i < 149)  r = sigmoidf_(v);
            else if (i < 151)  r = sigmoidf_(v);
            else               r = v;
            S[i] = r;
        }
        __syncthreads();
        mem_core(b, tid, S, phiS, mem, link, prec, rw, ww, usage, rvh, rvl, ost);
    } else {
        if (do_out) {
            float* red = smem;
            for (int tile = blk - B_; tile < 256; tile += B_) {
                gemm_plain_tile(tid, tile & 31, tile >> 5, red,
                    yh, yl, KOP_, woh, wol, KOP_, KOP_ / 32, bout, outp, T_ * IN_);
                __syncthreads();
            }
        }
        if (do_x) {
            for (int i = (blk - B_) * 256 + tid; i < B_ * IN_; i += B_ * 256) {
                int b = i >> 9, j = i & 511;
                float v = x[((size_t)b * T_ + tnext) * IN_ + j];
                split2(v, &xdh[(size_t)b * K1P_ + j], &xdl[(size_t)b * K1P_ + j]);
            }
        }
    }
}

// ---------------------------------------------------------------------------
extern "C" void kernel_launch(void* const* d_in, const int* in_sizes, int n_in,
                              void* d_out, int out_size, void* d_ws, size_t ws_size,
                              hipStream_t stream)
{
    const float* x       = (const float*)d_in[0];
    const float* W_ih0   = (const float*)d_in[1];
    const float* W_hh0   = (const float*)d_in[2];
    const float* b_ih0   = (const float*)d_in[3];
    const float* b_hh0   = (const float*)d_in[4];
    const float* W_ih1   = (const float*)d_in[5];
    const float* W_hh1   = (const float*)d_in[6];
    const float* b_ih1   = (const float*)d_in[7];
    const float* b_hh1   = (const float*)d_in[8];
    const float* W_iface = (const float*)d_in[9];
    const float* b_iface = (const float*)d_in[10];
    const float* W_out   = (const float*)d_in[11];
    const float* b_out   = (const float*)d_in[12];
    float* out = (float*)d_out;

    char* p = (char*)d_ws;
    auto alloc = [&](size_t bytes) { char* r = p; p += (bytes + 255) & ~(size_t)255; return r; };

    // ---- zero zone (memset each call) ----
    char* zstart = p;
    __bf16 *a1h[2][2], *a1l[2][2], *a2h[2][2], *a2l[2][2];
    for (int l = 0; l < 2; ++l)
        for (int q = 0; q < 2; ++q) {
            a1h[l][q] = (__bf16*)alloc(B_ * K1P_ * 2);
            a1l[l][q] = (__bf16*)alloc(B_ * K1P_ * 2);
        }
    for (int l = 0; l < 2; ++l)
        for (int q = 0; q < 2; ++q) {
            a2h[l][q] = (__bf16*)alloc(B_ * K2P_ * 2);
            a2l[l][q] = (__bf16*)alloc(B_ * K2P_ * 2);
        }
    __bf16* yinh = (__bf16*)alloc(B_ * KOP_ * 2);
    __bf16* yinl = (__bf16*)alloc(B_ * KOP_ * 2);
    float* cbuf   = (float*)alloc(4ull * B_ * H_ * 4);
    float* memv   = (float*)alloc(2ull * B_ * M_ * WC_ * 4);
    float* linkv  = (float*)alloc(2ull * B_ * M_ * M_ * 4);
    float* precv  = (float*)alloc(2ull * B_ * M_ * 4);
    float* rwv    = (float*)alloc(2ull * B_ * R_ * M_ * 4);
    float* wwv    = (float*)alloc(2ull * B_ * M_ * 4);
    float* usagev = (float*)alloc(2ull * B_ * M_ * 4);
    size_t zbytes = (size_t)(p - zstart);

    // ---- non-zero scratch (weights) ----
    __bf16 *w1h[2], *w1l[2], *w2h[2], *w2l[2];
    for (int l = 0; l < 2; ++l) { w1h[l] = (__bf16*)alloc(2048ull * K1P_ * 2); w1l[l] = (__bf16*)alloc(2048ull * K1P_ * 2); }
    for (int l = 0; l < 2; ++l) { w2h[l] = (__bf16*)alloc(2048ull * K2P_ * 2); w2l[l] = (__bf16*)alloc(2048ull * K2P_ * 2); }
    __bf16* wouth = (__bf16*)alloc(512ull * KOP_ * 2);
    __bf16* woutl = (__bf16*)alloc(512ull * KOP_ * 2);

    hipMemsetAsync(zstart, 0, zbytes, stream);

    for (int l = 0; l < 2; ++l) {
        conv_split<<<dim3((K1P_ + 255) / 256, 2048), 256, 0, stream>>>(
            W_ih0 + (size_t)l * 2048 * NNIN_, NNIN_, W_hh0 + (size_t)l * 2048 * H_, H_,
            2048, w1h[l], w1l[l], K1P_);
        conv_split<<<dim3((K2P_ + 255) / 256, 2048), 256, 0, stream>>>(
            W_ih1 + (size_t)l * 2048 * H_, H_, W_hh1 + (size_t)l * 2048 * H_, H_,
            2048, w2h[l], w2l[l], K2P_);
    }
    conv_split<<<dim3((KOP_ + 255) / 256, 512), 256, 0, stream>>>(
        W_out, NNIN_, nullptr, 0, 512, wouth, woutl, KOP_);
    build_inp<<<(B_ * IN_ + 255) / 256, 256, 0, stream>>>(x, a1h[0][0], a1l[0][0]);

    const dim3 gGate(32, 8);

    for (int t = 0; t < T_; ++t) {
        const int par = t & 1;
        for (int l = 0; l < 2; ++l) {
            float* c0 = cbuf + (size_t)(l * 2 + 0) * B_ * H_;
            float* c1 = cbuf + (size_t)(l * 2 + 1) * B_ * H_;
            __bf16* clh = (l == 0) ? a1h[1][par] : yinh;
            __bf16* cll = (l == 0) ? a1l[1][par] : yinl;
            const int clst = (l == 0) ? K1P_ : KOP_;

            // lstm cell A: reads a1[l][par]; h0 -> a2[l][par][0:512] and
            // h-state -> a1[l][par^1][592:1104]
            gemm_lstm16<<<gGate, 256, 0, stream>>>(
                a1h[l][par], a1l[l][par], K1P_, w1h[l], w1l[l], K1P_ / 32,
                b_ih0 + (size_t)l * 2048, b_hh0 + (size_t)l * 2048,
                c0,
                a2h[l][par], a2l[l][par], K2P_, 0,
                a1h[l][par ^ 1], a1l[l][par ^ 1], K1P_, NNIN_, 0);

            // lstm cell B: reads a2[l][par]; h1-state -> a2[l][par^1][512:1024];
            // clip(h1) -> next-consumer buffer cols [0:512)
            gemm_lstm16<<<gGate, 256, 0, stream>>>(
                a2h[l][par], a2l[l][par], K2P_, w2h[l], w2l[l], K2P_ / 32,
                b_ih1 + (size_t)l * 2048, b_hh1 + (size_t)l * 2048,
                c1,
                a2h[l][par ^ 1], a2l[l][par ^ 1], K2P_, H_,
                clh, cll, clst, 0, 1);

            // fused iface GEMV + mem step (+ out GEMM for t-1 when l==0,
            // + x(t+1) prefetch when l==1)
            ifmem<<<256, 256, 0, stream>>>(
                clh, cll, clst,
                W_iface + (size_t)l * IFACE_ * H_, b_iface + (size_t)l * IFACE_,
                memv + (size_t)l * B_ * M_ * WC_,
                linkv + (size_t)l * B_ * M_ * M_,
                precv + (size_t)l * B_ * M_,
                rwv + (size_t)l * B_ * R_ * M_,
                wwv + (size_t)l * B_ * M_,
                usagev + (size_t)l * B_ * M_,
                clh, cll,
                (l == 0 && t > 0) ? 1 : 0, yinh, yinl, wouth, woutl,
                b_out, out + (size_t)(t > 0 ? t - 1 : 0) * IN_,
                (l == 1 && t + 1 < T_) ? 1 : 0, x, t + 1,
                a1h[0][par ^ 1], a1l[0][par ^ 1]);
        }
    }

    // final y(T-1)
    gemm_plain16<<<dim3(32, 8), 256, 0, stream>>>(
        yinh, yinl, KOP_, wouth, woutl, KOP_, KOP_ / 32,
        b_out, out + (size_t)(T_ - 1) * IN_, T_ * IN_);
}

// Round 9
// 2511.834 us; speedup vs baseline: 3.7276x; 1.4055x over previous
//
#include <hip/hip_runtime.h>
#include <hip/hip_bf16.h>
#include <math.h>

#define B_ 128
#define T_ 32
#define IN_ 512
#define H_ 512
#define M_ 16
#define WC_ 20
#define R_ 4
#define RW_ 80
#define NNIN_ 592
#define IFACE_ 163
#define K1P_ 1120
#define K2P_ 1024
#define KOP_ 608
#define CLIP_ 20.0f
#define EPS_ 1e-6f
#define DELTA_ 5e-6f

typedef __bf16 bf16x8 __attribute__((ext_vector_type(8)));
typedef float f32x4 __attribute__((ext_vector_type(4)));

__device__ __forceinline__ float sigmoidf_(float x) { return 1.0f / (1.0f + expf(-x)); }
__device__ __forceinline__ float softplusf_(float x) {
    return fmaxf(x, 0.0f) + log1pf(expf(-fabsf(x)));
}
__device__ __forceinline__ void split2(float v, __bf16* hp, __bf16* lp) {
    __bf16 h = (__bf16)v;
    *hp = h;
    *lp = (__bf16)(v - (float)h);
}

// ---------------------------------------------------------------------------
// Parameter block for the slot kernel
// ---------------------------------------------------------------------------
struct P {
    const float *x, *bih0, *bhh0, *bih1, *bhh1, *Wif0, *Wif1, *bif0, *bif1, *bout;
    float* out;
    // rotated activation buffers [4]
    __bf16 *a10h[4], *a10l[4];   // [x | 0 | h00], stride K1P
    __bf16 *a11h[4], *a11l[4];   // [out0 | rv0 | h10], stride K1P
    __bf16 *a20h[4], *a20l[4];   // [h0A | h01], stride K2P
    __bf16 *a21h[4], *a21l[4];   // [h1A | h11], stride K2P
    __bf16 *yh[4],  *yl[4];      // [out1 | rv1 | pad], stride KOP
    float *c00, *c01, *c10, *c11;
    // DNC state, layer 0 / layer 1 (in-place RMW by their own stage)
    float *mem0, *link0, *prec0, *rw0, *ww0, *us0;
    float *mem1, *link1, *prec1, *rw1, *ww1, *us1;
    // split weights
    __bf16 *w10h, *w10l, *w20h, *w20l, *w11h, *w11l, *w21h, *w21l, *woh, *wol;
};

// ---------------------------------------------------------------------------
// Fused LSTM GEMM tile: 16x16 (batch x hidden) of all 4 gates, 4 waves split
// K, LDS reduce, wave0 runs LSTM pointwise epilogue.
// ---------------------------------------------------------------------------
__device__ __forceinline__ void gemm_lstm_tile(
    int tid, int jt, int mt, float* red,
    const __bf16* Ah, const __bf16* Al, int KS,
    const __bf16* Wh, const __bf16* Wl, int nsteps,
    const float* b1, const float* b2, float* cst,
    __bf16* d1h, __bf16* d1l, int st1, int off1,
    __bf16* d2h, __bf16* d2l, int st2, int off2, int clip2)
{
    const int wave = tid >> 6, lane = tid & 63;
    const int l15 = lane & 15, quad = lane >> 4;
    const int j0 = jt * 16, m0 = mt * 16;

    f32x4 acc[4];
    #pragma unroll
    for (int g = 0; g < 4; ++g)
        #pragma unroll
        for (int i = 0; i < 4; ++i) acc[g][i] = 0.f;

    const int ks = (wave * nsteps) >> 2;
    const int ke = ((wave + 1) * nsteps) >> 2;

    size_t aoff = (size_t)(m0 + l15) * KS + ks * 32 + quad * 8;
    size_t woff[4];
    #pragma unroll
    for (int g = 0; g < 4; ++g)
        woff[g] = (size_t)(g * 512 + j0 + l15) * KS + ks * 32 + quad * 8;

    for (int s = ks; s < ke; ++s) {
        bf16x8 ah = *(const bf16x8*)(Ah + aoff);
        bf16x8 al = *(const bf16x8*)(Al + aoff);
        aoff += 32;
        #pragma unroll
        for (int g = 0; g < 4; ++g) {
            bf16x8 wh = *(const bf16x8*)(Wh + woff[g]);
            bf16x8 wl = *(const bf16x8*)(Wl + woff[g]);
            woff[g] += 32;
            acc[g] = __builtin_amdgcn_mfma_f32_16x16x32_bf16(ah, wh, acc[g], 0, 0, 0);
            acc[g] = __builtin_amdgcn_mfma_f32_16x16x32_bf16(al, wh, acc[g], 0, 0, 0);
            acc[g] = __builtin_amdgcn_mfma_f32_16x16x32_bf16(ah, wl, acc[g], 0, 0, 0);
        }
    }

    if (wave > 0) {
        #pragma unroll
        for (int g = 0; g < 4; ++g)
            #pragma unroll
            for (int r = 0; r < 4; ++r)
                red[((g * 4 + r) * 3 + (wave - 1)) * 64 + lane] = acc[g][r];
    }
    __syncthreads();
    if (wave == 0) {
        const int col = j0 + l15;
        float bg[4];
        #pragma unroll
        for (int g = 0; g < 4; ++g) bg[g] = b1[g * 512 + col] + b2[g * 512 + col];
        #pragma unroll
        for (int r = 0; r < 4; ++r) {
            const int m = m0 + quad * 4 + r;
            float gv[4];
            #pragma unroll
            for (int g = 0; g < 4; ++g) {
                int i = g * 4 + r;
                gv[g] = acc[g][r] + red[(i * 3 + 0) * 64 + lane] + red[(i * 3 + 1) * 64 + lane]
                      + red[(i * 3 + 2) * 64 + lane] + bg[g];
            }
            float cold = cst[m * H_ + col];
            float cn = sigmoidf_(gv[1]) * cold + sigmoidf_(gv[0]) * tanhf(gv[2]);
            cst[m * H_ + col] = cn;
            float h = sigmoidf_(gv[3]) * tanhf(cn);
            split2(h, &d1h[(size_t)m * st1 + off1 + col], &d1l[(size_t)m * st1 + off1 + col]);
            float h2 = clip2 ? fminf(fmaxf(h, -CLIP_), CLIP_) : h;
            split2(h2, &d2h[(size_t)m * st2 + off2 + col], &d2l[(size_t)m * st2 + off2 + col]);
        }
    }
}

// ---------------------------------------------------------------------------
// Plain GEMM tile (out projection)
// ---------------------------------------------------------------------------
__device__ __forceinline__ void gemm_plain_tile(
    int tid, int nt, int mt, float* red,
    const __bf16* Ah, const __bf16* Al, int AS,
    const __bf16* Wh, const __bf16* Wl, int WS,
    int nsteps, const float* bias, float* C, int ldc)
{
    const int wave = tid >> 6, lane = tid & 63;
    const int l15 = lane & 15, quad = lane >> 4;
    const int n0 = nt * 16, m0 = mt * 16;

    f32x4 acc;
    #pragma unroll
    for (int i = 0; i < 4; ++i) acc[i] = 0.f;

    const int ks = (wave * nsteps) >> 2;
    const int ke = ((wave + 1) * nsteps) >> 2;

    size_t aoff = (size_t)(m0 + l15) * AS + ks * 32 + quad * 8;
    size_t woff = (size_t)(n0 + l15) * WS + ks * 32 + quad * 8;

    for (int s = ks; s < ke; ++s) {
        bf16x8 ah = *(const bf16x8*)(Ah + aoff);
        bf16x8 al = *(const bf16x8*)(Al + aoff);
        bf16x8 wh = *(const bf16x8*)(Wh + woff);
        bf16x8 wl = *(const bf16x8*)(Wl + woff);
        aoff += 32; woff += 32;
        acc = __builtin_amdgcn_mfma_f32_16x16x32_bf16(ah, wh, acc, 0, 0, 0);
        acc = __builtin_amdgcn_mfma_f32_16x16x32_bf16(al, wh, acc, 0, 0, 0);
        acc = __builtin_amdgcn_mfma_f32_16x16x32_bf16(ah, wl, acc, 0, 0, 0);
    }

    if (wave > 0) {
        #pragma unroll
        for (int r = 0; r < 4; ++r) red[(r * 3 + (wave - 1)) * 64 + lane] = acc[r];
    }
    __syncthreads();
    if (wave == 0) {
        const int col = n0 + l15;
        const float bc = bias[col];
        #pragma unroll
        for (int r = 0; r < 4; ++r) {
            const int m = m0 + quad * 4 + r;
            float v = acc[r] + red[(r * 3 + 0) * 64 + lane] + red[(r * 3 + 1) * 64 + lane]
                    + red[(r * 3 + 2) * 64 + lane] + bc;
            C[(size_t)m * ldc + col] = v;
        }
    }
}

// ---------------------------------------------------------------------------
// DNC memory-step core (one block per batch element, 256 threads). S[0..162]
// holds the transformed iface vector on entry.
// ---------------------------------------------------------------------------
__device__ void mem_core(int b, int tid, float* S, int* phi,
    float* mem, float* link, float* prec, float* rw,
    float* ww, float* usage, __bf16* rvh, __bf16* rvl, int rvst)
{
    float* sif = S;
    float* modes = S + 164;
    float* us = S + 176;
    float* wwold = S + 192;
    float* wwnew = S + 208;
    float* precold = S + 224;
    float* rwold = S + 240;
    float* rwnewS = S + 304;
    float* lnk = S + 368;
    float* memS = S + 624;
    float* wcw = S + 944;
    float* allocS = S + 960;
    float* rcw = S + 976;
    float* uu = S + 1040;
    float* sumww = S + 1056;

    if (tid < M_) {
        us[tid]      = usage[(size_t)b * M_ + tid];
        wwold[tid]   = ww[(size_t)b * M_ + tid];
        precold[tid] = prec[(size_t)b * M_ + tid];
    }
    if (tid < R_ * M_) rwold[tid] = rw[(size_t)b * R_ * M_ + tid];
    if (tid < M_ * M_) lnk[tid] = link[(size_t)b * M_ * M_ + tid];
    for (int i = tid; i < M_ * WC_; i += 256) memS[i] = mem[(size_t)b * M_ * WC_ + i];
    __syncthreads();

    if (tid < R_) {
        float a0 = sif[151 + tid * 3], a1 = sif[152 + tid * 3], a2 = sif[153 + tid * 3];
        float mx = fmaxf(a0, fmaxf(a1, a2));
        float e0 = expf(a0 - mx), e1 = expf(a1 - mx), e2 = expf(a2 - mx);
        float s = e0 + e1 + e2;
        modes[tid * 3 + 0] = e0 / s; modes[tid * 3 + 1] = e1 / s; modes[tid * 3 + 2] = e2 / s;
    }
    if (tid < M_) {
        float u = us[tid];
        u = u + (1.f - u) * wwold[tid];
        float psi = 1.f;
        #pragma unroll
        for (int r = 0; r < R_; ++r) psi *= (1.f - sif[145 + r] * rwold[r * 16 + tid]);
        u *= psi;
        us[tid] = u;
    }
    if (tid < M_) {
        float kn2 = 0.f, mn2 = 0.f, dot = 0.f;
        #pragma unroll
        for (int w = 0; w < WC_; ++w) {
            float kv = sif[84 + w], mv = memS[tid * WC_ + w];
            kn2 += kv * kv; mn2 += mv * mv; dot += kv * mv;
        }
        float c = dot / ((sqrtf(kn2) + EPS_) * (sqrtf(mn2) + EPS_));
        wcw[tid] = c * sif[104];
    }
    __syncthreads();

    if (tid == 0) {
        float mx = -1e30f;
        for (int m = 0; m < M_; ++m) mx = fmaxf(mx, wcw[m]);
        float s = 0.f;
        for (int m = 0; m < M_; ++m) { wcw[m] = expf(wcw[m] - mx); s += wcw[m]; }
        for (int m = 0; m < M_; ++m) wcw[m] /= s;
        for (int m = 0; m < M_; ++m) { uu[m] = DELTA_ + (1.f - DELTA_) * us[m]; phi[m] = m; }
        for (int j = 1; j < M_; ++j) {
            float key = uu[j]; int kp = phi[j];
            int i2 = j - 1;
            while (i2 >= 0 && uu[i2] > key) { uu[i2 + 1] = uu[i2]; phi[i2 + 1] = phi[i2]; --i2; }
            uu[i2 + 1] = key; phi[i2 + 1] = kp;
        }
        float prod = 1.f;
        for (int j = 0; j < M_; ++j) {
            float sa = (1.f - uu[j]) * prod;
            prod *= uu[j];
            allocS[phi[j]] = sa;
        }
    }
    __syncthreads();

    if (tid < M_) {
        wwnew[tid] = sif[150] * (sif[149] * allocS[tid] + (1.f - sif[149]) * wcw[tid]);
    }
    __syncthreads();

    if (tid == 0) {
        float s = 0.f;
        for (int m = 0; m < M_; ++m) s += wwnew[m];
        sumww[0] = s;
    }
    for (int i = tid; i < M_ * WC_; i += 256) {
        int m = i / WC_, w = i - m * WC_;
        float nm = memS[i] * (1.f - wwnew[m] * sif[105 + w]) + wwnew[m] * sif[125 + w];
        memS[i] = nm;
        mem[(size_t)b * M_ * WC_ + i] = nm;
    }
    __syncthreads();

    if (tid < M_ * M_) {
        int i = tid >> 4, j = tid & 15;
        float v = (1.f - wwnew[i] - wwnew[j]) * lnk[tid] + wwnew[i] * precold[j];
        if (i == j) v = 0.f;
        lnk[tid] = v;
        link[(size_t)b * M_ * M_ + tid] = v;
    }
    if (tid < M_) {
        prec[(size_t)b * M_ + tid] = (1.f - sumww[0]) * precold[tid] + wwnew[tid];
        usage[(size_t)b * M_ + tid] = us[tid];
        ww[(size_t)b * M_ + tid] = wwnew[tid];
    }
    __syncthreads();

    if (tid < 64) {
        int r = tid >> 4, m = tid & 15;
        float kn2 = 0.f, mn2 = 0.f, dot = 0.f;
        #pragma unroll
        for (int w = 0; w < WC_; ++w) {
            float kv = sif[r * WC_ + w], mv = memS[m * WC_ + w];
            kn2 += kv * kv; mn2 += mv * mv; dot += kv * mv;
        }
        float c = dot / ((sqrtf(kn2) + EPS_) * (sqrtf(mn2) + EPS_));
        rcw[r * 16 + m] = c * sif[80 + r];
    }
    __syncthreads();
    if (tid < R_) {
        float mx = -1e30f;
        for (int m = 0; m < M_; ++m) mx = fmaxf(mx, rcw[tid * 16 + m]);
        float s = 0.f;
        for (int m = 0; m < M_; ++m) { rcw[tid * 16 + m] = expf(rcw[tid * 16 + m] - mx); s += rcw[tid * 16 + m]; }
        for (int m = 0; m < M_; ++m) rcw[tid * 16 + m] /= s;
    }
    __syncthreads();

    if (tid < 64) {
        int r = tid >> 4, m = tid & 15;
        float fwd = 0.f, bwd = 0.f;
        #pragma unroll
        for (int j = 0; j < M_; ++j) fwd += lnk[m * 16 + j] * rwold[r * 16 + j];
        #pragma unroll
        for (int i = 0; i < M_; ++i) bwd += rwold[r * 16 + i] * lnk[i * 16 + m];
        float v = modes[r * 3 + 0] * bwd + modes[r * 3 + 1] * fwd + modes[r * 3 + 2] * rcw[r * 16 + m];
        rwnewS[r * 16 + m] = v;
        rw[(size_t)b * R_ * M_ + tid] = v;
    }
    __syncthreads();

    if (tid < RW_) {
        int r = tid / WC_, w = tid - r * WC_;
        float s = 0.f;
        #pragma unroll
        for (int m = 0; m < M_; ++m) s += rwnewS[r * 16 + m] * memS[m * WC_ + w];
        split2(s, &rvh[(size_t)b * rvst + IN_ + tid], &rvl[(size_t)b * rvst + IN_ + tid]);
    }
}

// iface GEMV + mem step, one block per batch row
__device__ void mem_group(int b, int tid, float* smem, int* phiS,
    const __bf16* och, const __bf16* ocl, int ost,
    const float* Wif, const float* bif,
    float* mem, float* link, float* prec, float* rw, float* ww, float* usage,
    __bf16* rvh, __bf16* rvl)
{
    float* af = smem;        // 512
    float* S  = smem + 512;  // 1057
    for (int i = tid; i < 512; i += 256)
        af[i] = (float)och[(size_t)b * ost + i] + (float)ocl[(size_t)b * ost + i];
    __syncthreads();
    if (tid < IFACE_) {
        const float* wr = Wif + (size_t)tid * 512;
        float acc = 0.f;
        for (int k = 0; k < 512; k += 4)
            acc += af[k] * wr[k] + af[k + 1] * wr[k + 1]
                 + af[k + 2] * wr[k + 2] + af[k + 3] * wr[k + 3];
        float v = acc + bif[tid];
        int i = tid;
        float r;
        if (i < 80)        r = tanhf(v);
        else if (i < 84)   r = softplusf_(v);
        else if (i < 104)  r = tanhf(v);
        else if (i < 105)  r = softplusf_(v);
        else if (i < 125)  r = sigmoidf_(v);
        else if (i < 145)  r = tanhf(v);
        else if (i < 149)  r = sigmoidf_(v);
        else if (i < 151)  r = sigmoidf_(v);
        else               r = v;
        S[i] = r;
    }
    __syncthreads();
    mem_core(b, tid, S, phiS, mem, link, prec, rw, ww, usage, rvh, rvl, ost);
}

// ---------------------------------------------------------------------------
// One pipeline slot: all 7 stage instances + x-prefetch, mutually independent.
//   blocks [0,256):      A0(t=s)        lstm cell A, layer 0
//   blocks [256,512):    B0(t=s-1)      lstm cell B, layer 0
//   blocks [512,640):    M0(t=s-2)      iface+mem, layer 0
//   blocks [640,896):    A1(t=s-3)      lstm cell A, layer 1
//   blocks [896,1152):   B1(t=s-4)      lstm cell B, layer 1
//   blocks [1152,1280):  M1(t=s-5)      iface+mem, layer 1
//   blocks [1280,1312):  Y(t=s-6)       output GEMM (8 tiles each)
//   blocks [1312,1344):  x(s+1) convert
// ---------------------------------------------------------------------------
__global__ __launch_bounds__(256) void slot_kernel(P p, int s)
{
    __shared__ float smem[3072];
    __shared__ int phiS[16];
    const int blk = blockIdx.x, tid = threadIdx.x;

    if (blk < 256) {                       // A0(t=s)
        int t = s;
        if (t < T_) {
            gemm_lstm_tile(tid, blk & 31, blk >> 5, smem,
                p.a10h[t & 3], p.a10l[t & 3], K1P_, p.w10h, p.w10l, K1P_ / 32,
                p.bih0, p.bhh0, p.c00,
                p.a10h[(t + 1) & 3], p.a10l[(t + 1) & 3], K1P_, NNIN_,
                p.a20h[t & 3], p.a20l[t & 3], K2P_, 0, 0);
        }
    } else if (blk < 512) {                // B0(t=s-1)
        int t = s - 1;
        if (t >= 0 && t < T_) {
            int b2 = blk - 256;
            gemm_lstm_tile(tid, b2 & 31, b2 >> 5, smem,
                p.a20h[t & 3], p.a20l[t & 3], K2P_, p.w20h, p.w20l, K2P_ / 32,
                p.bih1, p.bhh1, p.c01,
                p.a20h[(t + 1) & 3], p.a20l[(t + 1) & 3], K2P_, H_,
                p.a11h[t & 3], p.a11l[t & 3], K1P_, 0, 1);
        }
    } else if (blk < 640) {                // M0(t=s-2)
        int t = s - 2;
        if (t >= 0 && t < T_) {
            mem_group(blk - 512, tid, smem, phiS,
                p.a11h[t & 3], p.a11l[t & 3], K1P_,
                p.Wif0, p.bif0,
                p.mem0, p.link0, p.prec0, p.rw0, p.ww0, p.us0,
                p.a11h[t & 3], p.a11l[t & 3]);
        }
    } else if (blk < 896) {                // A1(t=s-3)
        int t = s - 3;
        if (t >= 0 && t < T_) {
            int b2 = blk - 640;
            gemm_lstm_tile(tid, b2 & 31, b2 >> 5, smem,
                p.a11h[t & 3], p.a11l[t & 3], K1P_, p.w11h, p.w11l, K1P_ / 32,
                p.bih0 + 2048, p.bhh0 + 2048, p.c10,
                p.a11h[(t + 1) & 3], p.a11l[(t + 1) & 3], K1P_, NNIN_,
                p.a21h[t & 3], p.a21l[t & 3], K2P_, 0, 0);
        }
    } else if (blk < 1152) {               // B1(t=s-4)
        int t = s - 4;
        if (t >= 0 && t < T_) {
            int b2 = blk - 896;
            gemm_lstm_tile(tid, b2 & 31, b2 >> 5, smem,
                p.a21h[t & 3], p.a21l[t & 3], K2P_, p.w21h, p.w21l, K2P_ / 32,
                p.bih1 + 2048, p.bhh1 + 2048, p.c11,
                p.a21h[(t + 1) & 3], p.a21l[(t + 1) & 3], K2P_, H_,
                p.yh[t & 3], p.yl[t & 3], KOP_, 0, 1);
        }
    } else if (blk < 1280) {               // M1(t=s-5)
        int t = s - 5;
        if (t >= 0 && t < T_) {
            mem_group(blk - 1152, tid, smem, phiS,
                p.yh[t & 3], p.yl[t & 3], KOP_,
                p.Wif1, p.bif1,
                p.mem1, p.link1, p.prec1, p.rw1, p.ww1, p.us1,
                p.yh[t & 3], p.yl[t & 3]);
        }
    } else if (blk < 1312) {               // Y(t=s-6)
        int t = s - 6;
        if (t >= 0 && t < T_) {
            for (int tile = blk - 1280; tile < 256; tile += 32) {
                gemm_plain_tile(tid, tile & 31, tile >> 5, smem,
                    p.yh[t & 3], p.yl[t & 3], KOP_, p.woh, p.wol, KOP_, KOP_ / 32,
                    p.bout, p.out + (size_t)t * IN_, T_ * IN_);
                __syncthreads();
            }
        }
    } else {                               // x(s+1) convert
        int tn = s + 1;
        if (tn < T_) {
            for (int i = (blk - 1312) * 256 + tid; i < B_ * IN_; i += 32 * 256) {
                int b = i >> 9, j = i & 511;
                float v = p.x[((size_t)b * T_ + tn) * IN_ + j];
                split2(v, &p.a10h[tn & 3][(size_t)b * K1P_ + j],
                          &p.a10l[tn & 3][(size_t)b * K1P_ + j]);
            }
        }
    }
}

// ---------------------------------------------------------------------------
// Setup kernels
// ---------------------------------------------------------------------------
__global__ __launch_bounds__(256) void conv_split(
    const float* __restrict__ s1, int K1, const float* __restrict__ s2, int K2,
    int Nsrc, __bf16* __restrict__ hi, __bf16* __restrict__ lo, int Kd)
{
    int k = blockIdx.x * 256 + threadIdx.x;
    int n = blockIdx.y;
    if (k >= Kd) return;
    float v = 0.f;
    if (n < Nsrc) {
        if (k < K1) v = s1[(size_t)n * K1 + k];
        else if (k < K1 + K2) v = s2[(size_t)n * K2 + (k - K1)];
    }
    __bf16 h = (__bf16)v;
    hi[(size_t)n * Kd + k] = h;
    lo[(size_t)n * Kd + k] = (__bf16)(v - (float)h);
}

__global__ __launch_bounds__(256) void build_inp(const float* __restrict__ x,
                                                 __bf16* __restrict__ a1h,
                                                 __bf16* __restrict__ a1l)
{
    int idx = blockIdx.x * 256 + threadIdx.x;
    if (idx >= B_ * IN_) return;
    int b = idx >> 9, j = idx & 511;
    float v = x[(size_t)b * T_ * IN_ + j];
    split2(v, &a1h[b * K1P_ + j], &a1l[b * K1P_ + j]);
}

// ---------------------------------------------------------------------------
extern "C" void kernel_launch(void* const* d_in, const int* in_sizes, int n_in,
                              void* d_out, int out_size, void* d_ws, size_t ws_size,
                              hipStream_t stream)
{
    const float* x       = (const float*)d_in[0];
    const float* W_ih0   = (const float*)d_in[1];
    const float* W_hh0   = (const float*)d_in[2];
    const float* b_ih0   = (const float*)d_in[3];
    const float* b_hh0   = (const float*)d_in[4];
    const float* W_ih1   = (const float*)d_in[5];
    const float* W_hh1   = (const float*)d_in[6];
    const float* b_ih1   = (const float*)d_in[7];
    const float* b_hh1   = (const float*)d_in[8];
    const float* W_iface = (const float*)d_in[9];
    const float* b_iface = (const float*)d_in[10];
    const float* W_out   = (const float*)d_in[11];
    const float* b_out   = (const float*)d_in[12];

    P p;
    p.x = x;
    p.bih0 = b_ih0; p.bhh0 = b_hh0; p.bih1 = b_ih1; p.bhh1 = b_hh1;
    p.Wif0 = W_iface; p.Wif1 = W_iface + (size_t)IFACE_ * H_;
    p.bif0 = b_iface; p.bif1 = b_iface + IFACE_;
    p.bout = b_out;
    p.out = (float*)d_out;

    char* ptr = (char*)d_ws;
    auto alloc = [&](size_t bytes) { char* r = ptr; ptr += (bytes + 255) & ~(size_t)255; return r; };

    // ---- zero zone (memset each call) ----
    char* zstart = ptr;
    for (int q = 0; q < 4; ++q) { p.a10h[q] = (__bf16*)alloc(B_ * K1P_ * 2); p.a10l[q] = (__bf16*)alloc(B_ * K1P_ * 2); }
    for (int q = 0; q < 4; ++q) { p.a11h[q] = (__bf16*)alloc(B_ * K1P_ * 2); p.a11l[q] = (__bf16*)alloc(B_ * K1P_ * 2); }
    for (int q = 0; q < 4; ++q) { p.a20h[q] = (__bf16*)alloc(B_ * K2P_ * 2); p.a20l[q] = (__bf16*)alloc(B_ * K2P_ * 2); }
    for (int q = 0; q < 4; ++q) { p.a21h[q] = (__bf16*)alloc(B_ * K2P_ * 2); p.a21l[q] = (__bf16*)alloc(B_ * K2P_ * 2); }
    for (int q = 0; q < 4; ++q) { p.yh[q]  = (__bf16*)alloc(B_ * KOP_ * 2);  p.yl[q]  = (__bf16*)alloc(B_ * KOP_ * 2); }
    p.c00 = (float*)alloc((size_t)B_ * H_ * 4);
    p.c01 = (float*)alloc((size_t)B_ * H_ * 4);
    p.c10 = (float*)alloc((size_t)B_ * H_ * 4);
    p.c11 = (float*)alloc((size_t)B_ * H_ * 4);
    p.mem0  = (float*)alloc((size_t)B_ * M_ * WC_ * 4);
    p.link0 = (float*)alloc((size_t)B_ * M_ * M_ * 4);
    p.prec0 = (float*)alloc((size_t)B_ * M_ * 4);
    p.rw0   = (float*)alloc((size_t)B_ * R_ * M_ * 4);
    p.ww0   = (float*)alloc((size_t)B_ * M_ * 4);
    p.us0   = (float*)alloc((size_t)B_ * M_ * 4);
    p.mem1  = (float*)alloc((size_t)B_ * M_ * WC_ * 4);
    p.link1 = (float*)alloc((size_t)B_ * M_ * M_ * 4);
    p.prec1 = (float*)alloc((size_t)B_ * M_ * 4);
    p.rw1   = (float*)alloc((size_t)B_ * R_ * M_ * 4);
    p.ww1   = (float*)alloc((size_t)B_ * M_ * 4);
    p.us1   = (float*)alloc((size_t)B_ * M_ * 4);
    size_t zbytes = (size_t)(ptr - zstart);

    // ---- weights (rewritten every call) ----
    p.w10h = (__bf16*)alloc(2048ull * K1P_ * 2); p.w10l = (__bf16*)alloc(2048ull * K1P_ * 2);
    p.w11h = (__bf16*)alloc(2048ull * K1P_ * 2); p.w11l = (__bf16*)alloc(2048ull * K1P_ * 2);
    p.w20h = (__bf16*)alloc(2048ull * K2P_ * 2); p.w20l = (__bf16*)alloc(2048ull * K2P_ * 2);
    p.w21h = (__bf16*)alloc(2048ull * K2P_ * 2); p.w21l = (__bf16*)alloc(2048ull * K2P_ * 2);
    p.woh  = (__bf16*)alloc(512ull * KOP_ * 2);  p.wol  = (__bf16*)alloc(512ull * KOP_ * 2);

    hipMemsetAsync(zstart, 0, zbytes, stream);

    conv_split<<<dim3((K1P_ + 255) / 256, 2048), 256, 0, stream>>>(
        W_ih0, NNIN_, W_hh0, H_, 2048, p.w10h, p.w10l, K1P_);
    conv_split<<<dim3((K1P_ + 255) / 256, 2048), 256, 0, stream>>>(
        W_ih0 + 2048ull * NNIN_, NNIN_, W_hh0 + 2048ull * H_, H_, 2048, p.w11h, p.w11l, K1P_);
    conv_split<<<dim3((K2P_ + 255) / 256, 2048), 256, 0, stream>>>(
        W_ih1, H_, W_hh1, H_, 2048, p.w20h, p.w20l, K2P_);
    conv_split<<<dim3((K2P_ + 255) / 256, 2048), 256, 0, stream>>>(
        W_ih1 + 2048ull * H_, H_, W_hh1 + 2048ull * H_, H_, 2048, p.w21h, p.w21l, K2P_);
    conv_split<<<dim3((KOP_ + 255) / 256, 512), 256, 0, stream>>>(
        W_out, NNIN_, nullptr, 0, 512, p.woh, p.wol, KOP_);
    build_inp<<<(B_ * IN_ + 255) / 256, 256, 0, stream>>>(x, p.a10h[0], p.a10l[0]);

    // 38 pipeline slots cover t=0..31 for all 7 stages
    for (int s = 0; s < T_ + 6; ++s) {
        slot_kernel<<<1344, 256, 0, stream>>>(p, s);
    }
}

// Round 10
// 2401.278 us; speedup vs baseline: 3.8992x; 1.0460x over previous
//
#include <hip/hip_runtime.h>
#include <hip/hip_bf16.h>
#include <math.h>

#define B_ 128
#define T_ 32
#define IN_ 512
#define H_ 512
#define M_ 16
#define WC_ 20
#define R_ 4
#define RW_ 80
#define NNIN_ 592
#define IFACE_ 163
#define K1P_ 1120
#define K2P_ 1024
#define KOP_ 608
#define CLIP_ 20.0f
#define EPS_ 1e-6f
#define DELTA_ 5e-6f

typedef __bf16 bf16x8 __attribute__((ext_vector_type(8)));
typedef float f32x4 __attribute__((ext_vector_type(4)));

__device__ __forceinline__ float sigmoidf_(float x) { return 1.0f / (1.0f + expf(-x)); }
__device__ __forceinline__ float softplusf_(float x) {
    return fmaxf(x, 0.0f) + log1pf(expf(-fabsf(x)));
}
__device__ __forceinline__ void split2(float v, __bf16* hp, __bf16* lp) {
    __bf16 h = (__bf16)v;
    *hp = h;
    *lp = (__bf16)(v - (float)h);
}

// ---------------------------------------------------------------------------
// Parameter block for the slot kernel
// ---------------------------------------------------------------------------
struct P {
    const float *x, *bih0, *bhh0, *bih1, *bhh1, *Wif0, *Wif1, *bif0, *bif1, *bout;
    float* out;
    __bf16 *a10h[4], *a10l[4];   // [x | 0 | h00], stride K1P
    __bf16 *a11h[4], *a11l[4];   // [out0 | rv0 | h10], stride K1P
    __bf16 *a20h[4], *a20l[4];   // [h0A | h01], stride K2P
    __bf16 *a21h[4], *a21l[4];   // [h1A | h11], stride K2P
    __bf16 *yh[4],  *yl[4];      // [out1 | rv1 | pad], stride KOP
    float *c00, *c01, *c10, *c11;
    float *mem0, *link0, *prec0, *rw0, *ww0, *us0;
    float *mem1, *link1, *prec1, *rw1, *ww1, *us1;
    __bf16 *w10h, *w10l, *w20h, *w20l, *w11h, *w11l, *w21h, *w21l, *woh, *wol;
};

// ---------------------------------------------------------------------------
// Fused LSTM GEMM tile: 16x16 (batch x hidden) of all 4 gates, 4 waves split
// K, LDS reduce, wave0 runs LSTM pointwise epilogue.
// ---------------------------------------------------------------------------
__device__ __forceinline__ void gemm_lstm_tile(
    int tid, int jt, int mt, float* red,
    const __bf16* Ah, const __bf16* Al, int KS,
    const __bf16* Wh, const __bf16* Wl, int nsteps,
    const float* b1, const float* b2, float* cst,
    __bf16* d1h, __bf16* d1l, int st1, int off1,
    __bf16* d2h, __bf16* d2l, int st2, int off2, int clip2)
{
    const int wave = tid >> 6, lane = tid & 63;
    const int l15 = lane & 15, quad = lane >> 4;
    const int j0 = jt * 16, m0 = mt * 16;

    f32x4 acc[4];
    #pragma unroll
    for (int g = 0; g < 4; ++g)
        #pragma unroll
        for (int i = 0; i < 4; ++i) acc[g][i] = 0.f;

    const int ks = (wave * nsteps) >> 2;
    const int ke = ((wave + 1) * nsteps) >> 2;

    size_t aoff = (size_t)(m0 + l15) * KS + ks * 32 + quad * 8;
    size_t woff[4];
    #pragma unroll
    for (int g = 0; g < 4; ++g)
        woff[g] = (size_t)(g * 512 + j0 + l15) * KS + ks * 32 + quad * 8;

    for (int s = ks; s < ke; ++s) {
        bf16x8 ah = *(const bf16x8*)(Ah + aoff);
        bf16x8 al = *(const bf16x8*)(Al + aoff);
        aoff += 32;
        #pragma unroll
        for (int g = 0; g < 4; ++g) {
            bf16x8 wh = *(const bf16x8*)(Wh + woff[g]);
            bf16x8 wl = *(const bf16x8*)(Wl + woff[g]);
            woff[g] += 32;
            acc[g] = __builtin_amdgcn_mfma_f32_16x16x32_bf16(ah, wh, acc[g], 0, 0, 0);
            acc[g] = __builtin_amdgcn_mfma_f32_16x16x32_bf16(al, wh, acc[g], 0, 0, 0);
            acc[g] = __builtin_amdgcn_mfma_f32_16x16x32_bf16(ah, wl, acc[g], 0, 0, 0);
        }
    }

    if (wave > 0) {
        #pragma unroll
        for (int g = 0; g < 4; ++g)
            #pragma unroll
            for (int r = 0; r < 4; ++r)
                red[((g * 4 + r) * 3 + (wave - 1)) * 64 + lane] = acc[g][r];
    }
    __syncthreads();
    if (wave == 0) {
        const int col = j0 + l15;
        float bg[4];
        #pragma unroll
        for (int g = 0; g < 4; ++g) bg[g] = b1[g * 512 + col] + b2[g * 512 + col];
        #pragma unroll
        for (int r = 0; r < 4; ++r) {
            const int m = m0 + quad * 4 + r;
            float gv[4];
            #pragma unroll
            for (int g = 0; g < 4; ++g) {
                int i = g * 4 + r;
                gv[g] = acc[g][r] + red[(i * 3 + 0) * 64 + lane] + red[(i * 3 + 1) * 64 + lane]
                      + red[(i * 3 + 2) * 64 + lane] + bg[g];
            }
            float cold = cst[m * H_ + col];
            float cn = sigmoidf_(gv[1]) * cold + sigmoidf_(gv[0]) * tanhf(gv[2]);
            cst[m * H_ + col] = cn;
            float h = sigmoidf_(gv[3]) * tanhf(cn);
            split2(h, &d1h[(size_t)m * st1 + off1 + col], &d1l[(size_t)m * st1 + off1 + col]);
            float h2 = clip2 ? fminf(fmaxf(h, -CLIP_), CLIP_) : h;
            split2(h2, &d2h[(size_t)m * st2 + off2 + col], &d2l[(size_t)m * st2 + off2 + col]);
        }
    }
}

// ---------------------------------------------------------------------------
// Plain GEMM tile (out projection)
// ---------------------------------------------------------------------------
__device__ __forceinline__ void gemm_plain_tile(
    int tid, int nt, int mt, float* red,
    const __bf16* Ah, const __bf16* Al, int AS,
    const __bf16* Wh, const __bf16* Wl, int WS,
    int nsteps, const float* bias, float* C, int ldc)
{
    const int wave = tid >> 6, lane = tid & 63;
    const int l15 = lane & 15, quad = lane >> 4;
    const int n0 = nt * 16, m0 = mt * 16;

    f32x4 acc;
    #pragma unroll
    for (int i = 0; i < 4; ++i) acc[i] = 0.f;

    const int ks = (wave * nsteps) >> 2;
    const int ke = ((wave + 1) * nsteps) >> 2;

    size_t aoff = (size_t)(m0 + l15) * AS + ks * 32 + quad * 8;
    size_t woff = (size_t)(n0 + l15) * WS + ks * 32 + quad * 8;

    for (int s = ks; s < ke; ++s) {
        bf16x8 ah = *(const bf16x8*)(Ah + aoff);
        bf16x8 al = *(const bf16x8*)(Al + aoff);
        bf16x8 wh = *(const bf16x8*)(Wh + woff);
        bf16x8 wl = *(const bf16x8*)(Wl + woff);
        aoff += 32; woff += 32;
        acc = __builtin_amdgcn_mfma_f32_16x16x32_bf16(ah, wh, acc, 0, 0, 0);
        acc = __builtin_amdgcn_mfma_f32_16x16x32_bf16(al, wh, acc, 0, 0, 0);
        acc = __builtin_amdgcn_mfma_f32_16x16x32_bf16(ah, wl, acc, 0, 0, 0);
    }

    if (wave > 0) {
        #pragma unroll
        for (int r = 0; r < 4; ++r) red[(r * 3 + (wave - 1)) * 64 + lane] = acc[r];
    }
    __syncthreads();
    if (wave == 0) {
        const int col = n0 + l15;
        const float bc = bias[col];
        #pragma unroll
        for (int r = 0; r < 4; ++r) {
            const int m = m0 + quad * 4 + r;
            float v = acc[r] + red[(r * 3 + 0) * 64 + lane] + red[(r * 3 + 1) * 64 + lane]
                    + red[(r * 3 + 2) * 64 + lane] + bc;
            C[(size_t)m * ldc + col] = v;
        }
    }
}

// ---------------------------------------------------------------------------
// DNC memory-step core (one block per batch element, 256 threads). S[0..162]
// holds the transformed iface vector on entry.
// ---------------------------------------------------------------------------
__device__ void mem_core(int b, int tid, float* S, int* phi,
    float* mem, float* link, float* prec, float* rw,
    float* ww, float* usage, __bf16* rvh, __bf16* rvl, int rvst)
{
    float* sif = S;
    float* modes = S + 164;
    float* us = S + 176;
    float* wwold = S + 192;
    float* wwnew = S + 208;
    float* precold = S + 224;
    float* rwold = S + 240;
    float* rwnewS = S + 304;
    float* lnk = S + 368;
    float* memS = S + 624;
    float* wcw = S + 944;
    float* allocS = S + 960;
    float* rcw = S + 976;
    float* uu = S + 1040;
    float* sumww = S + 1056;

    if (tid < M_) {
        us[tid]      = usage[(size_t)b * M_ + tid];
        wwold[tid]   = ww[(size_t)b * M_ + tid];
        precold[tid] = prec[(size_t)b * M_ + tid];
    }
    if (tid < R_ * M_) rwold[tid] = rw[(size_t)b * R_ * M_ + tid];
    if (tid < M_ * M_) lnk[tid] = link[(size_t)b * M_ * M_ + tid];
    for (int i = tid; i < M_ * WC_; i += 256) memS[i] = mem[(size_t)b * M_ * WC_ + i];
    __syncthreads();

    if (tid < R_) {
        float a0 = sif[151 + tid * 3], a1 = sif[152 + tid * 3], a2 = sif[153 + tid * 3];
        float mx = fmaxf(a0, fmaxf(a1, a2));
        float e0 = expf(a0 - mx), e1 = expf(a1 - mx), e2 = expf(a2 - mx);
        float s = e0 + e1 + e2;
        modes[tid * 3 + 0] = e0 / s; modes[tid * 3 + 1] = e1 / s; modes[tid * 3 + 2] = e2 / s;
    }
    if (tid < M_) {
        float u = us[tid];
        u = u + (1.f - u) * wwold[tid];
        float psi = 1.f;
        #pragma unroll
        for (int r = 0; r < R_; ++r) psi *= (1.f - sif[145 + r] * rwold[r * 16 + tid]);
        u *= psi;
        us[tid] = u;
    }
    if (tid < M_) {
        float kn2 = 0.f, mn2 = 0.f, dot = 0.f;
        #pragma unroll
        for (int w = 0; w < WC_; ++w) {
            float kv = sif[84 + w], mv = memS[tid * WC_ + w];
            kn2 += kv * kv; mn2 += mv * mv; dot += kv * mv;
        }
        float c = dot / ((sqrtf(kn2) + EPS_) * (sqrtf(mn2) + EPS_));
        wcw[tid] = c * sif[104];
    }
    __syncthreads();

    if (tid == 0) {
        float mx = -1e30f;
        for (int m = 0; m < M_; ++m) mx = fmaxf(mx, wcw[m]);
        float s = 0.f;
        for (int m = 0; m < M_; ++m) { wcw[m] = expf(wcw[m] - mx); s += wcw[m]; }
        for (int m = 0; m < M_; ++m) wcw[m] /= s;
        for (int m = 0; m < M_; ++m) { uu[m] = DELTA_ + (1.f - DELTA_) * us[m]; phi[m] = m; }
        for (int j = 1; j < M_; ++j) {
            float key = uu[j]; int kp = phi[j];
            int i2 = j - 1;
            while (i2 >= 0 && uu[i2] > key) { uu[i2 + 1] = uu[i2]; phi[i2 + 1] = phi[i2]; --i2; }
            uu[i2 + 1] = key; phi[i2 + 1] = kp;
        }
        float prod = 1.f;
        for (int j = 0; j < M_; ++j) {
            float sa = (1.f - uu[j]) * prod;
            prod *= uu[j];
            allocS[phi[j]] = sa;
        }
    }
    __syncthreads();

    if (tid < M_) {
        wwnew[tid] = sif[150] * (sif[149] * allocS[tid] + (1.f - sif[149]) * wcw[tid]);
    }
    __syncthreads();

    if (tid == 0) {
        float s = 0.f;
        for (int m = 0; m < M_; ++m) s += wwnew[m];
        sumww[0] = s;
    }
    for (int i = tid; i < M_ * WC_; i += 256) {
        int m = i / WC_, w = i - m * WC_;
        float nm = memS[i] * (1.f - wwnew[m] * sif[105 + w]) + wwnew[m] * sif[125 + w];
        memS[i] = nm;
        mem[(size_t)b * M_ * WC_ + i] = nm;
    }
    __syncthreads();

    if (tid < M_ * M_) {
        int i = tid >> 4, j = tid & 15;
        float v = (1.f - wwnew[i] - wwnew[j]) * lnk[tid] + wwnew[i] * precold[j];
        if (i == j) v = 0.f;
        lnk[tid] = v;
        link[(size_t)b * M_ * M_ + tid] = v;
    }
    if (tid < M_) {
        prec[(size_t)b * M_ + tid] = (1.f - sumww[0]) * precold[tid] + wwnew[tid];
        usage[(size_t)b * M_ + tid] = us[tid];
        ww[(size_t)b * M_ + tid] = wwnew[tid];
    }
    __syncthreads();

    if (tid < 64) {
        int r = tid >> 4, m = tid & 15;
        float kn2 = 0.f, mn2 = 0.f, dot = 0.f;
        #pragma unroll
        for (int w = 0; w < WC_; ++w) {
            float kv = sif[r * WC_ + w], mv = memS[m * WC_ + w];
            kn2 += kv * kv; mn2 += mv * mv; dot += kv * mv;
        }
        float c = dot / ((sqrtf(kn2) + EPS_) * (sqrtf(mn2) + EPS_));
        rcw[r * 16 + m] = c * sif[80 + r];
    }
    __syncthreads();
    if (tid < R_) {
        float mx = -1e30f;
        for (int m = 0; m < M_; ++m) mx = fmaxf(mx, rcw[tid * 16 + m]);
        float s = 0.f;
        for (int m = 0; m < M_; ++m) { rcw[tid * 16 + m] = expf(rcw[tid * 16 + m] - mx); s += rcw[tid * 16 + m]; }
        for (int m = 0; m < M_; ++m) rcw[tid * 16 + m] /= s;
    }
    __syncthreads();

    if (tid < 64) {
        int r = tid >> 4, m = tid & 15;
        float fwd = 0.f, bwd = 0.f;
        #pragma unroll
        for (int j = 0; j < M_; ++j) fwd += lnk[m * 16 + j] * rwold[r * 16 + j];
        #pragma unroll
        for (int i = 0; i < M_; ++i) bwd += rwold[r * 16 + i] * lnk[i * 16 + m];
        float v = modes[r * 3 + 0] * bwd + modes[r * 3 + 1] * fwd + modes[r * 3 + 2] * rcw[r * 16 + m];
        rwnewS[r * 16 + m] = v;
        rw[(size_t)b * R_ * M_ + tid] = v;
    }
    __syncthreads();

    if (tid < RW_) {
        int r = tid / WC_, w = tid - r * WC_;
        float s = 0.f;
        #pragma unroll
        for (int m = 0; m < M_; ++m) s += rwnewS[r * 16 + m] * memS[m * WC_ + w];
        split2(s, &rvh[(size_t)b * rvst + IN_ + tid], &rvl[(size_t)b * rvst + IN_ + tid]);
    }
}

// ---------------------------------------------------------------------------
// iface GEMV (coalesced, wave-per-output + shuffle reduce) + mem step.
// One block per batch row.
// ---------------------------------------------------------------------------
__device__ void mem_group(int b, int tid, float* smem, int* phiS,
    const __bf16* och, const __bf16* ocl, int ost,
    const float* Wif, const float* bif,
    float* mem, float* link, float* prec, float* rw, float* ww, float* usage,
    __bf16* rvh, __bf16* rvl)
{
    float* af = smem;        // 512
    float* S  = smem + 512;  // 1057
    for (int i = tid; i < 512; i += 256)
        af[i] = (float)och[(size_t)b * ost + i] + (float)ocl[(size_t)b * ost + i];
    __syncthreads();

    const int wave = tid >> 6, lane = tid & 63;
    float av[8];
    #pragma unroll
    for (int i = 0; i < 8; ++i) av[i] = af[lane * 8 + i];

    for (int o = wave; o < IFACE_; o += 4) {
        const float* wr = Wif + (size_t)o * 512 + lane * 8;
        float acc = 0.f;
        #pragma unroll
        for (int i = 0; i < 8; ++i) acc += av[i] * wr[i];
        #pragma unroll
        for (int off = 32; off > 0; off >>= 1)
            acc += __shfl_down(acc, off);
        if (lane == 0) {
            float v = acc + bif[o];
            float r;
            if (o < 80)        r = tanhf(v);
            else if (o < 84)   r = softplusf_(v);
            else if (o < 104)  r = tanhf(v);
            else if (o < 105)  r = softplusf_(v);
            else if (o < 125)  r = sigmoidf_(v);
            else if (o < 145)  r = tanhf(v);
            else if (o < 149)  r = sigmoidf_(v);
            else if (o < 151)  r = sigmoidf_(v);
            else               r = v;
            S[o] = r;
        }
    }
    __syncthreads();
    mem_core(b, tid, S, phiS, mem, link, prec, rw, ww, usage, rvh, rvl, ost);
}

// ---------------------------------------------------------------------------
// One pipeline slot: all 7 stage instances + x-prefetch, mutually independent.
//   [0,256):      A0(t=s)
//   [256,512):    B0(t=s-1)
//   [512,640):    M0(t=s-2)
//   [640,896):    A1(t=s-3)
//   [896,1152):   B1(t=s-4)
//   [1152,1280):  M1(t=s-5)
//   [1280,1536):  Y(t=s-6), one 16x16 tile each
//   [1536,1568):  x(s+1) convert
// ---------------------------------------------------------------------------
__global__ __launch_bounds__(256) void slot_kernel(P p, int s)
{
    __shared__ float smem[3072];
    __shared__ int phiS[16];
    const int blk = blockIdx.x, tid = threadIdx.x;

    if (blk < 256) {                       // A0(t=s)
        int t = s;
        if (t < T_) {
            gemm_lstm_tile(tid, blk & 31, blk >> 5, smem,
                p.a10h[t & 3], p.a10l[t & 3], K1P_, p.w10h, p.w10l, K1P_ / 32,
                p.bih0, p.bhh0, p.c00,
                p.a10h[(t + 1) & 3], p.a10l[(t + 1) & 3], K1P_, NNIN_,
                p.a20h[t & 3], p.a20l[t & 3], K2P_, 0, 0);
        }
    } else if (blk < 512) {                // B0(t=s-1)
        int t = s - 1;
        if (t >= 0 && t < T_) {
            int b2 = blk - 256;
            gemm_lstm_tile(tid, b2 & 31, b2 >> 5, smem,
                p.a20h[t & 3], p.a20l[t & 3], K2P_, p.w20h, p.w20l, K2P_ / 32,
                p.bih1, p.bhh1, p.c01,
                p.a20h[(t + 1) & 3], p.a20l[(t + 1) & 3], K2P_, H_,
                p.a11h[t & 3], p.a11l[t & 3], K1P_, 0, 1);
        }
    } else if (blk < 640) {                // M0(t=s-2)
        int t = s - 2;
        if (t >= 0 && t < T_) {
            mem_group(blk - 512, tid, smem, phiS,
                p.a11h[t & 3], p.a11l[t & 3], K1P_,
                p.Wif0, p.bif0,
                p.mem0, p.link0, p.prec0, p.rw0, p.ww0, p.us0,
                p.a11h[t & 3], p.a11l[t & 3]);
        }
    } else if (blk < 896) {                // A1(t=s-3)
        int t = s - 3;
        if (t >= 0 && t < T_) {
            int b2 = blk - 640;
            gemm_lstm_tile(tid, b2 & 31, b2 >> 5, smem,
                p.a11h[t & 3], p.a11l[t & 3], K1P_, p.w11h, p.w11l, K1P_ / 32,
                p.bih0 + 2048, p.bhh0 + 2048, p.c10,
                p.a11h[(t + 1) & 3], p.a11l[(t + 1) & 3], K1P_, NNIN_,
                p.a21h[t & 3], p.a21l[t & 3], K2P_, 0, 0);
        }
    } else if (blk < 1152) {               // B1(t=s-4)
        int t = s - 4;
        if (t >= 0 && t < T_) {
            int b2 = blk - 896;
            gemm_lstm_tile(tid, b2 & 31, b2 >> 5, smem,
                p.a21h[t & 3], p.a21l[t & 3], K2P_, p.w21h, p.w21l, K2P_ / 32,
                p.bih1 + 2048, p.bhh1 + 2048, p.c11,
                p.a21h[(t + 1) & 3], p.a21l[(t + 1) & 3], K2P_, H_,
                p.yh[t & 3], p.yl[t & 3], KOP_, 0, 1);
        }
    } else if (blk < 1280) {               // M1(t=s-5)
        int t = s - 5;
        if (t >= 0 && t < T_) {
            mem_group(blk - 1152, tid, smem, phiS,
                p.yh[t & 3], p.yl[t & 3], KOP_,
                p.Wif1, p.bif1,
                p.mem1, p.link1, p.prec1, p.rw1, p.ww1, p.us1,
                p.yh[t & 3], p.yl[t & 3]);
        }
    } else if (blk < 1536) {               // Y(t=s-6), one tile per block
        int t = s - 6;
        if (t >= 0 && t < T_) {
            int tile = blk - 1280;
            gemm_plain_tile(tid, tile & 31, tile >> 5, smem,
                p.yh[t & 3], p.yl[t & 3], KOP_, p.woh, p.wol, KOP_, KOP_ / 32,
                p.bout, p.out + (size_t)t * IN_, T_ * IN_);
        }
    } else {                               // x(s+1) convert
        int tn = s + 1;
        if (tn < T_) {
            for (int i = (blk - 1536) * 256 + tid; i < B_ * IN_; i += 32 * 256) {
                int b = i >> 9, j = i & 511;
                float v = p.x[((size_t)b * T_ + tn) * IN_ + j];
                split2(v, &p.a10h[tn & 3][(size_t)b * K1P_ + j],
                          &p.a10l[tn & 3][(size_t)b * K1P_ + j]);
            }
        }
    }
}

// ---------------------------------------------------------------------------
// Setup kernels
// ---------------------------------------------------------------------------
__global__ __launch_bounds__(256) void conv_split(
    const float* __restrict__ s1, int K1, const float* __restrict__ s2, int K2,
    int Nsrc, __bf16* __restrict__ hi, __bf16* __restrict__ lo, int Kd)
{
    int k = blockIdx.x * 256 + threadIdx.x;
    int n = blockIdx.y;
    if (k >= Kd) return;
    float v = 0.f;
    if (n < Nsrc) {
        if (k < K1) v = s1[(size_t)n * K1 + k];
        else if (k < K1 + K2) v = s2[(size_t)n * K2 + (k - K1)];
    }
    __bf16 h = (__bf16)v;
    hi[(size_t)n * Kd + k] = h;
    lo[(size_t)n * Kd + k] = (__bf16)(v - (float)h);
}

__global__ __launch_bounds__(256) void build_inp(const float* __restrict__ x,
                                                 __bf16* __restrict__ a1h,
                                                 __bf16* __restrict__ a1l)
{
    int idx = blockIdx.x * 256 + threadIdx.x;
    if (idx >= B_ * IN_) return;
    int b = idx >> 9, j = idx & 511;
    float v = x[(size_t)b * T_ * IN_ + j];
    split2(v, &a1h[b * K1P_ + j], &a1l[b * K1P_ + j]);
}

// ---------------------------------------------------------------------------
extern "C" void kernel_launch(void* const* d_in, const int* in_sizes, int n_in,
                              void* d_out, int out_size, void* d_ws, size_t ws_size,
                              hipStream_t stream)
{
    const float* x       = (const float*)d_in[0];
    const float* W_ih0   = (const float*)d_in[1];
    const float* W_hh0   = (const float*)d_in[2];
    const float* b_ih0   = (const float*)d_in[3];
    const float* b_hh0   = (const float*)d_in[4];
    const float* W_ih1   = (const float*)d_in[5];
    const float* W_hh1   = (const float*)d_in[6];
    const float* b_ih1   = (const float*)d_in[7];
    const float* b_hh1   = (const float*)d_in[8];
    const float* W_iface = (const float*)d_in[9];
    const float* b_iface = (const float*)d_in[10];
    const float* W_out   = (const float*)d_in[11];
    const float* b_out   = (const float*)d_in[12];

    P p;
    p.x = x;
    p.bih0 = b_ih0; p.bhh0 = b_hh0; p.bih1 = b_ih1; p.bhh1 = b_hh1;
    p.Wif0 = W_iface; p.Wif1 = W_iface + (size_t)IFACE_ * H_;
    p.bif0 = b_iface; p.bif1 = b_iface + IFACE_;
    p.bout = b_out;
    p.out = (float*)d_out;

    char* ptr = (char*)d_ws;
    auto alloc = [&](size_t bytes) { char* r = ptr; ptr += (bytes + 255) & ~(size_t)255; return r; };

    // ---- zero zone (memset each call) ----
    char* zstart = ptr;
    for (int q = 0; q < 4; ++q) { p.a10h[q] = (__bf16*)alloc(B_ * K1P_ * 2); p.a10l[q] = (__bf16*)alloc(B_ * K1P_ * 2); }
    for (int q = 0; q < 4; ++q) { p.a11h[q] = (__bf16*)alloc(B_ * K1P_ * 2); p.a11l[q] = (__bf16*)alloc(B_ * K1P_ * 2); }
    for (int q = 0; q < 4; ++q) { p.a20h[q] = (__bf16*)alloc(B_ * K2P_ * 2); p.a20l[q] = (__bf16*)alloc(B_ * K2P_ * 2); }
    for (int q = 0; q < 4; ++q) { p.a21h[q] = (__bf16*)alloc(B_ * K2P_ * 2); p.a21l[q] = (__bf16*)alloc(B_ * K2P_ * 2); }
    for (int q = 0; q < 4; ++q) { p.yh[q]  = (__bf16*)alloc(B_ * KOP_ * 2);  p.yl[q]  = (__bf16*)alloc(B_ * KOP_ * 2); }
    p.c00 = (float*)alloc((size_t)B_ * H_ * 4);
    p.c01 = (float*)alloc((size_t)B_ * H_ * 4);
    p.c10 = (float*)alloc((size_t)B_ * H_ * 4);
    p.c11 = (float*)alloc((size_t)B_ * H_ * 4);
    p.mem0  = (float*)alloc((size_t)B_ * M_ * WC_ * 4);
    p.link0 = (float*)alloc((size_t)B_ * M_ * M_ * 4);
    p.prec0 = (float*)alloc((size_t)B_ * M_ * 4);
    p.rw0   = (float*)alloc((size_t)B_ * R_ * M_ * 4);
    p.ww0   = (float*)alloc((size_t)B_ * M_ * 4);
    p.us0   = (float*)alloc((size_t)B_ * M_ * 4);
    p.mem1  = (float*)alloc((size_t)B_ * M_ * WC_ * 4);
    p.link1 = (float*)alloc((size_t)B_ * M_ * M_ * 4);
    p.prec1 = (float*)alloc((size_t)B_ * M_ * 4);
    p.rw1   = (float*)alloc((size_t)B_ * R_ * M_ * 4);
    p.ww1   = (float*)alloc((size_t)B_ * M_ * 4);
    p.us1   = (float*)alloc((size_t)B_ * M_ * 4);
    size_t zbytes = (size_t)(ptr - zstart);

    // ---- weights (rewritten every call) ----
    p.w10h = (__bf16*)alloc(2048ull * K1P_ * 2); p.w10l = (__bf16*)alloc(2048ull * K1P_ * 2);
    p.w11h = (__bf16*)alloc(2048ull * K1P_ * 2); p.w11l = (__bf16*)alloc(2048ull * K1P_ * 2);
    p.w20h = (__bf16*)alloc(2048ull * K2P_ * 2); p.w20l = (__bf16*)alloc(2048ull * K2P_ * 2);
    p.w21h = (__bf16*)alloc(2048ull * K2P_ * 2); p.w21l = (__bf16*)alloc(2048ull * K2P_ * 2);
    p.woh  = (__bf16*)alloc(512ull * KOP_ * 2);  p.wol  = (__bf16*)alloc(512ull * KOP_ * 2);

    hipMemsetAsync(zstart, 0, zbytes, stream);

    conv_split<<<dim3((K1P_ + 255) / 256, 2048), 256, 0, stream>>>(
        W_ih0, NNIN_, W_hh0, H_, 2048, p.w10h, p.w10l, K1P_);
    conv_split<<<dim3((K1P_ + 255) / 256, 2048), 256, 0, stream>>>(
        W_ih0 + 2048ull * NNIN_, NNIN_, W_hh0 + 2048ull * H_, H_, 2048, p.w11h, p.w11l, K1P_);
    conv_split<<<dim3((K2P_ + 255) / 256, 2048), 256, 0, stream>>>(
        W_ih1, H_, W_hh1, H_, 2048, p.w20h, p.w20l, K2P_);
    conv_split<<<dim3((K2P_ + 255) / 256, 2048), 256, 0, stream>>>(
        W_ih1 + 2048ull * H_, H_, W_hh1 + 2048ull * H_, H_, 2048, p.w21h, p.w21l, K2P_);
    conv_split<<<dim3((KOP_ + 255) / 256, 512), 256, 0, stream>>>(
        W_out, NNIN_, nullptr, 0, 512, p.woh, p.wol, KOP_);
    build_inp<<<(B_ * IN_ + 255) / 256, 256, 0, stream>>>(x, p.a10h[0], p.a10l[0]);

    // 38 pipeline slots cover t=0..31 for all 7 stages
    for (int s = 0; s < T_ + 6; ++s) {
        slot_kernel<<<1568, 256, 0, stream>>>(p, s);
    }
}

// Round 11
// 2068.574 us; speedup vs baseline: 4.5264x; 1.1608x over previous
//
#include <hip/hip_runtime.h>
#include <hip/hip_bf16.h>
#include <math.h>

#define B_ 128
#define T_ 32
#define IN_ 512
#define H_ 512
#define M_ 16
#define WC_ 20
#define R_ 4
#define RW_ 80
#define NNIN_ 592
#define IFACE_ 163
#define K1P_ 1120
#define K2P_ 1024
#define KOP_ 608
#define CLIP_ 20.0f
#define EPS_ 1e-6f
#define DELTA_ 5e-6f

typedef __bf16 bf16x8 __attribute__((ext_vector_type(8)));
typedef float f32x4 __attribute__((ext_vector_type(4)));

__device__ __forceinline__ float sigmoidf_(float x) { return 1.0f / (1.0f + expf(-x)); }
__device__ __forceinline__ float softplusf_(float x) {
    return fmaxf(x, 0.0f) + log1pf(expf(-fabsf(x)));
}
__device__ __forceinline__ void split2(float v, __bf16* hp, __bf16* lp) {
    __bf16 h = (__bf16)v;
    *hp = h;
    *lp = (__bf16)(v - (float)h);
}

// ---------------------------------------------------------------------------
// Parameter block for the slot kernel. Weights: single bf16 limb (hi only);
// activations remain split hi/lo.
// ---------------------------------------------------------------------------
struct P {
    const float *x, *bih0, *bhh0, *bih1, *bhh1, *Wif0, *Wif1, *bif0, *bif1, *bout;
    float* out;
    __bf16 *a10h[4], *a10l[4];   // [x | 0 | h00], stride K1P
    __bf16 *a11h[4], *a11l[4];   // [out0 | rv0 | h10], stride K1P
    __bf16 *a20h[4], *a20l[4];   // [h0A | h01], stride K2P
    __bf16 *a21h[4], *a21l[4];   // [h1A | h11], stride K2P
    __bf16 *yh[4],  *yl[4];      // [out1 | rv1 | pad], stride KOP
    float *c00, *c01, *c10, *c11;
    float *mem0, *link0, *prec0, *rw0, *ww0, *us0;
    float *mem1, *link1, *prec1, *rw1, *ww1, *us1;
    __bf16 *w10, *w20, *w11, *w21, *wo;
};

// ---------------------------------------------------------------------------
// Fused LSTM GEMM tile: 16x16 (batch x hidden) of all 4 gates, 4 waves split
// K, LDS reduce, wave0 runs LSTM pointwise epilogue. W single-limb:
// acc += ah*w + al*w (2 MFMAs).
// ---------------------------------------------------------------------------
__device__ __forceinline__ void gemm_lstm_tile(
    int tid, int jt, int mt, float* red,
    const __bf16* Ah, const __bf16* Al, int KS,
    const __bf16* W, int nsteps,
    const float* b1, const float* b2, float* cst,
    __bf16* d1h, __bf16* d1l, int st1, int off1,
    __bf16* d2h, __bf16* d2l, int st2, int off2, int clip2)
{
    const int wave = tid >> 6, lane = tid & 63;
    const int l15 = lane & 15, quad = lane >> 4;
    const int j0 = jt * 16, m0 = mt * 16;

    f32x4 acc[4];
    #pragma unroll
    for (int g = 0; g < 4; ++g)
        #pragma unroll
        for (int i = 0; i < 4; ++i) acc[g][i] = 0.f;

    const int ks = (wave * nsteps) >> 2;
    const int ke = ((wave + 1) * nsteps) >> 2;

    size_t aoff = (size_t)(m0 + l15) * KS + ks * 32 + quad * 8;
    size_t woff[4];
    #pragma unroll
    for (int g = 0; g < 4; ++g)
        woff[g] = (size_t)(g * 512 + j0 + l15) * KS + ks * 32 + quad * 8;

    for (int s = ks; s < ke; ++s) {
        bf16x8 ah = *(const bf16x8*)(Ah + aoff);
        bf16x8 al = *(const bf16x8*)(Al + aoff);
        aoff += 32;
        #pragma unroll
        for (int g = 0; g < 4; ++g) {
            bf16x8 wh = *(const bf16x8*)(W + woff[g]);
            woff[g] += 32;
            acc[g] = __builtin_amdgcn_mfma_f32_16x16x32_bf16(ah, wh, acc[g], 0, 0, 0);
            acc[g] = __builtin_amdgcn_mfma_f32_16x16x32_bf16(al, wh, acc[g], 0, 0, 0);
        }
    }

    if (wave > 0) {
        #pragma unroll
        for (int g = 0; g < 4; ++g)
            #pragma unroll
            for (int r = 0; r < 4; ++r)
                red[((g * 4 + r) * 3 + (wave - 1)) * 64 + lane] = acc[g][r];
    }
    __syncthreads();
    if (wave == 0) {
        const int col = j0 + l15;
        float bg[4];
        #pragma unroll
        for (int g = 0; g < 4; ++g) bg[g] = b1[g * 512 + col] + b2[g * 512 + col];
        #pragma unroll
        for (int r = 0; r < 4; ++r) {
            const int m = m0 + quad * 4 + r;
            float gv[4];
            #pragma unroll
            for (int g = 0; g < 4; ++g) {
                int i = g * 4 + r;
                gv[g] = acc[g][r] + red[(i * 3 + 0) * 64 + lane] + red[(i * 3 + 1) * 64 + lane]
                      + red[(i * 3 + 2) * 64 + lane] + bg[g];
            }
            float cold = cst[m * H_ + col];
            float cn = sigmoidf_(gv[1]) * cold + sigmoidf_(gv[0]) * tanhf(gv[2]);
            cst[m * H_ + col] = cn;
            float h = sigmoidf_(gv[3]) * tanhf(cn);
            split2(h, &d1h[(size_t)m * st1 + off1 + col], &d1l[(size_t)m * st1 + off1 + col]);
            float h2 = clip2 ? fminf(fmaxf(h, -CLIP_), CLIP_) : h;
            split2(h2, &d2h[(size_t)m * st2 + off2 + col], &d2l[(size_t)m * st2 + off2 + col]);
        }
    }
}

// ---------------------------------------------------------------------------
// Plain GEMM tile (out projection), W single-limb
// ---------------------------------------------------------------------------
__device__ __forceinline__ void gemm_plain_tile(
    int tid, int nt, int mt, float* red,
    const __bf16* Ah, const __bf16* Al, int AS,
    const __bf16* W, int WS,
    int nsteps, const float* bias, float* C, int ldc)
{
    const int wave = tid >> 6, lane = tid & 63;
    const int l15 = lane & 15, quad = lane >> 4;
    const int n0 = nt * 16, m0 = mt * 16;

    f32x4 acc;
    #pragma unroll
    for (int i = 0; i < 4; ++i) acc[i] = 0.f;

    const int ks = (wave * nsteps) >> 2;
    const int ke = ((wave + 1) * nsteps) >> 2;

    size_t aoff = (size_t)(m0 + l15) * AS + ks * 32 + quad * 8;
    size_t woff = (size_t)(n0 + l15) * WS + ks * 32 + quad * 8;

    for (int s = ks; s < ke; ++s) {
        bf16x8 ah = *(const bf16x8*)(Ah + aoff);
        bf16x8 al = *(const bf16x8*)(Al + aoff);
        bf16x8 wh = *(const bf16x8*)(W + woff);
        aoff += 32; woff += 32;
        acc = __builtin_amdgcn_mfma_f32_16x16x32_bf16(ah, wh, acc, 0, 0, 0);
        acc = __builtin_amdgcn_mfma_f32_16x16x32_bf16(al, wh, acc, 0, 0, 0);
    }

    if (wave > 0) {
        #pragma unroll
        for (int r = 0; r < 4; ++r) red[(r * 3 + (wave - 1)) * 64 + lane] = acc[r];
    }
    __syncthreads();
    if (wave == 0) {
        const int col = n0 + l15;
        const float bc = bias[col];
        #pragma unroll
        for (int r = 0; r < 4; ++r) {
            const int m = m0 + quad * 4 + r;
            float v = acc[r] + red[(r * 3 + 0) * 64 + lane] + red[(r * 3 + 1) * 64 + lane]
                    + red[(r * 3 + 2) * 64 + lane] + bc;
            C[(size_t)m * ldc + col] = v;
        }
    }
}

// ---------------------------------------------------------------------------
// DNC memory-step core (one block per batch element, 256 threads). S[0..162]
// holds the transformed iface vector on entry.
// ---------------------------------------------------------------------------
__device__ void mem_core(int b, int tid, float* S, int* phi,
    float* mem, float* link, float* prec, float* rw,
    float* ww, float* usage, __bf16* rvh, __bf16* rvl, int rvst)
{
    float* sif = S;
    float* modes = S + 164;
    float* us = S + 176;
    float* wwold = S + 192;
    float* wwnew = S + 208;
    float* precold = S + 224;
    float* rwold = S + 240;
    float* rwnewS = S + 304;
    float* lnk = S + 368;
    float* memS = S + 624;
    float* wcw = S + 944;
    float* allocS = S + 960;
    float* rcw = S + 976;
    float* uu = S + 1040;
    float* sumww = S + 1056;

    if (tid < M_) {
        us[tid]      = usage[(size_t)b * M_ + tid];
        wwold[tid]   = ww[(size_t)b * M_ + tid];
        precold[tid] = prec[(size_t)b * M_ + tid];
    }
    if (tid < R_ * M_) rwold[tid] = rw[(size_t)b * R_ * M_ + tid];
    if (tid < M_ * M_) lnk[tid] = link[(size_t)b * M_ * M_ + tid];
    for (int i = tid; i < M_ * WC_; i += 256) memS[i] = mem[(size_t)b * M_ * WC_ + i];
    __syncthreads();

    if (tid < R_) {
        float a0 = sif[151 + tid * 3], a1 = sif[152 + tid * 3], a2 = sif[153 + tid * 3];
        float mx = fmaxf(a0, fmaxf(a1, a2));
        float e0 = expf(a0 - mx), e1 = expf(a1 - mx), e2 = expf(a2 - mx);
        float s = e0 + e1 + e2;
        modes[tid * 3 + 0] = e0 / s; modes[tid * 3 + 1] = e1 / s; modes[tid * 3 + 2] = e2 / s;
    }
    if (tid < M_) {
        float u = us[tid];
        u = u + (1.f - u) * wwold[tid];
        float psi = 1.f;
        #pragma unroll
        for (int r = 0; r < R_; ++r) psi *= (1.f - sif[145 + r] * rwold[r * 16 + tid]);
        u *= psi;
        us[tid] = u;
    }
    if (tid < M_) {
        float kn2 = 0.f, mn2 = 0.f, dot = 0.f;
        #pragma unroll
        for (int w = 0; w < WC_; ++w) {
            float kv = sif[84 + w], mv = memS[tid * WC_ + w];
            kn2 += kv * kv; mn2 += mv * mv; dot += kv * mv;
        }
        float c = dot / ((sqrtf(kn2) + EPS_) * (sqrtf(mn2) + EPS_));
        wcw[tid] = c * sif[104];
    }
    __syncthreads();

    if (tid == 0) {
        float mx = -1e30f;
        for (int m = 0; m < M_; ++m) mx = fmaxf(mx, wcw[m]);
        float s = 0.f;
        for (int m = 0; m < M_; ++m) { wcw[m] = expf(wcw[m] - mx); s += wcw[m]; }
        for (int m = 0; m < M_; ++m) wcw[m] /= s;
        for (int m = 0; m < M_; ++m) { uu[m] = DELTA_ + (1.f - DELTA_) * us[m]; phi[m] = m; }
        for (int j = 1; j < M_; ++j) {
            float key = uu[j]; int kp = phi[j];
            int i2 = j - 1;
            while (i2 >= 0 && uu[i2] > key) { uu[i2 + 1] = uu[i2]; phi[i2 + 1] = phi[i2]; --i2; }
            uu[i2 + 1] = key; phi[i2 + 1] = kp;
        }
        float prod = 1.f;
        for (int j = 0; j < M_; ++j) {
            float sa = (1.f - uu[j]) * prod;
            prod *= uu[j];
            allocS[phi[j]] = sa;
        }
    }
    __syncthreads();

    if (tid < M_) {
        wwnew[tid] = sif[150] * (sif[149] * allocS[tid] + (1.f - sif[149]) * wcw[tid]);
    }
    __syncthreads();

    if (tid == 0) {
        float s = 0.f;
        for (int m = 0; m < M_; ++m) s += wwnew[m];
        sumww[0] = s;
    }
    for (int i = tid; i < M_ * WC_; i += 256) {
        int m = i / WC_, w = i - m * WC_;
        float nm = memS[i] * (1.f - wwnew[m] * sif[105 + w]) + wwnew[m] * sif[125 + w];
        memS[i] = nm;
        mem[(size_t)b * M_ * WC_ + i] = nm;
    }
    __syncthreads();

    if (tid < M_ * M_) {
        int i = tid >> 4, j = tid & 15;
        float v = (1.f - wwnew[i] - wwnew[j]) * lnk[tid] + wwnew[i] * precold[j];
        if (i == j) v = 0.f;
        lnk[tid] = v;
        link[(size_t)b * M_ * M_ + tid] = v;
    }
    if (tid < M_) {
        prec[(size_t)b * M_ + tid] = (1.f - sumww[0]) * precold[tid] + wwnew[tid];
        usage[(size_t)b * M_ + tid] = us[tid];
        ww[(size_t)b * M_ + tid] = wwnew[tid];
    }
    __syncthreads();

    if (tid < 64) {
        int r = tid >> 4, m = tid & 15;
        float kn2 = 0.f, mn2 = 0.f, dot = 0.f;
        #pragma unroll
        for (int w = 0; w < WC_; ++w) {
            float kv = sif[r * WC_ + w], mv = memS[m * WC_ + w];
            kn2 += kv * kv; mn2 += mv * mv; dot += kv * mv;
        }
        float c = dot / ((sqrtf(kn2) + EPS_) * (sqrtf(mn2) + EPS_));
        rcw[r * 16 + m] = c * sif[80 + r];
    }
    __syncthreads();
    if (tid < R_) {
        float mx = -1e30f;
        for (int m = 0; m < M_; ++m) mx = fmaxf(mx, rcw[tid * 16 + m]);
        float s = 0.f;
        for (int m = 0; m < M_; ++m) { rcw[tid * 16 + m] = expf(rcw[tid * 16 + m] - mx); s += rcw[tid * 16 + m]; }
        for (int m = 0; m < M_; ++m) rcw[tid * 16 + m] /= s;
    }
    __syncthreads();

    if (tid < 64) {
        int r = tid >> 4, m = tid & 15;
        float fwd = 0.f, bwd = 0.f;
        #pragma unroll
        for (int j = 0; j < M_; ++j) fwd += lnk[m * 16 + j] * rwold[r * 16 + j];
        #pragma unroll
        for (int i = 0; i < M_; ++i) bwd += rwold[r * 16 + i] * lnk[i * 16 + m];
        float v = modes[r * 3 + 0] * bwd + modes[r * 3 + 1] * fwd + modes[r * 3 + 2] * rcw[r * 16 + m];
        rwnewS[r * 16 + m] = v;
        rw[(size_t)b * R_ * M_ + tid] = v;
    }
    __syncthreads();

    if (tid < RW_) {
        int r = tid / WC_, w = tid - r * WC_;
        float s = 0.f;
        #pragma unroll
        for (int m = 0; m < M_; ++m) s += rwnewS[r * 16 + m] * memS[m * WC_ + w];
        split2(s, &rvh[(size_t)b * rvst + IN_ + tid], &rvl[(size_t)b * rvst + IN_ + tid]);
    }
}

// ---------------------------------------------------------------------------
// iface GEMV (coalesced, wave-per-output + shuffle reduce) + mem step.
// ---------------------------------------------------------------------------
__device__ void mem_group(int b, int tid, float* smem, int* phiS,
    const __bf16* och, const __bf16* ocl, int ost,
    const float* Wif, const float* bif,
    float* mem, float* link, float* prec, float* rw, float* ww, float* usage,
    __bf16* rvh, __bf16* rvl)
{
    float* af = smem;        // 512
    float* S  = smem + 512;  // 1057
    for (int i = tid; i < 512; i += 256)
        af[i] = (float)och[(size_t)b * ost + i] + (float)ocl[(size_t)b * ost + i];
    __syncthreads();

    const int wave = tid >> 6, lane = tid & 63;
    float av[8];
    #pragma unroll
    for (int i = 0; i < 8; ++i) av[i] = af[lane * 8 + i];

    for (int o = wave; o < IFACE_; o += 4) {
        const float* wr = Wif + (size_t)o * 512 + lane * 8;
        float acc = 0.f;
        #pragma unroll
        for (int i = 0; i < 8; ++i) acc += av[i] * wr[i];
        #pragma unroll
        for (int off = 32; off > 0; off >>= 1)
            acc += __shfl_down(acc, off);
        if (lane == 0) {
            float v = acc + bif[o];
            float r;
            if (o < 80)        r = tanhf(v);
            else if (o < 84)   r = softplusf_(v);
            else if (o < 104)  r = tanhf(v);
            else if (o < 105)  r = softplusf_(v);
            else if (o < 125)  r = sigmoidf_(v);
            else if (o < 145)  r = tanhf(v);
            else if (o < 149)  r = sigmoidf_(v);
            else if (o < 151)  r = sigmoidf_(v);
            else               r = v;
            S[o] = r;
        }
    }
    __syncthreads();
    mem_core(b, tid, S, phiS, mem, link, prec, rw, ww, usage, rvh, rvl, ost);
}

// ---------------------------------------------------------------------------
// One pipeline slot: 7 independent stage instances + x-prefetch.
//   [0,256):      A0(t=s)
//   [256,512):    B0(t=s-1)
//   [512,640):    M0(t=s-2)
//   [640,896):    A1(t=s-3)
//   [896,1152):   B1(t=s-4)
//   [1152,1280):  M1(t=s-5)
//   [1280,1536):  Y(t=s-6)
//   [1536,1568):  x(s+1) convert
// ---------------------------------------------------------------------------
__global__ __launch_bounds__(256) void slot_kernel(P p, int s)
{
    __shared__ float smem[3072];
    __shared__ int phiS[16];
    const int blk = blockIdx.x, tid = threadIdx.x;

    if (blk < 256) {                       // A0(t=s)
        int t = s;
        if (t < T_) {
            gemm_lstm_tile(tid, blk & 31, blk >> 5, smem,
                p.a10h[t & 3], p.a10l[t & 3], K1P_, p.w10, K1P_ / 32,
                p.bih0, p.bhh0, p.c00,
                p.a10h[(t + 1) & 3], p.a10l[(t + 1) & 3], K1P_, NNIN_,
                p.a20h[t & 3], p.a20l[t & 3], K2P_, 0, 0);
        }
    } else if (blk < 512) {                // B0(t=s-1)
        int t = s - 1;
        if (t >= 0 && t < T_) {
            int b2 = blk - 256;
            gemm_lstm_tile(tid, b2 & 31, b2 >> 5, smem,
                p.a20h[t & 3], p.a20l[t & 3], K2P_, p.w20, K2P_ / 32,
                p.bih1, p.bhh1, p.c01,
                p.a20h[(t + 1) & 3], p.a20l[(t + 1) & 3], K2P_, H_,
                p.a11h[t & 3], p.a11l[t & 3], K1P_, 0, 1);
        }
    } else if (blk < 640) {                // M0(t=s-2)
        int t = s - 2;
        if (t >= 0 && t < T_) {
            mem_group(blk - 512, tid, smem, phiS,
                p.a11h[t & 3], p.a11l[t & 3], K1P_,
                p.Wif0, p.bif0,
                p.mem0, p.link0, p.prec0, p.rw0, p.ww0, p.us0,
                p.a11h[t & 3], p.a11l[t & 3]);
        }
    } else if (blk < 896) {                // A1(t=s-3)
        int t = s - 3;
        if (t >= 0 && t < T_) {
            int b2 = blk - 640;
            gemm_lstm_tile(tid, b2 & 31, b2 >> 5, smem,
                p.a11h[t & 3], p.a11l[t & 3], K1P_, p.w11, K1P_ / 32,
                p.bih0 + 2048, p.bhh0 + 2048, p.c10,
                p.a11h[(t + 1) & 3], p.a11l[(t + 1) & 3], K1P_, NNIN_,
                p.a21h[t & 3], p.a21l[t & 3], K2P_, 0, 0);
        }
    } else if (blk < 1152) {               // B1(t=s-4)
        int t = s - 4;
        if (t >= 0 && t < T_) {
            int b2 = blk - 896;
            gemm_lstm_tile(tid, b2 & 31, b2 >> 5, smem,
                p.a21h[t & 3], p.a21l[t & 3], K2P_, p.w21, K2P_ / 32,
                p.bih1 + 2048, p.bhh1 + 2048, p.c11,
                p.a21h[(t + 1) & 3], p.a21l[(t + 1) & 3], K2P_, H_,
                p.yh[t & 3], p.yl[t & 3], KOP_, 0, 1);
        }
    } else if (blk < 1280) {               // M1(t=s-5)
        int t = s - 5;
        if (t >= 0 && t < T_) {
            mem_group(blk - 1152, tid, smem, phiS,
                p.yh[t & 3], p.yl[t & 3], KOP_,
                p.Wif1, p.bif1,
                p.mem1, p.link1, p.prec1, p.rw1, p.ww1, p.us1,
                p.yh[t & 3], p.yl[t & 3]);
        }
    } else if (blk < 1536) {               // Y(t=s-6)
        int t = s - 6;
        if (t >= 0 && t < T_) {
            int tile = blk - 1280;
            gemm_plain_tile(tid, tile & 31, tile >> 5, smem,
                p.yh[t & 3], p.yl[t & 3], KOP_, p.wo, KOP_, KOP_ / 32,
                p.bout, p.out + (size_t)t * IN_, T_ * IN_);
        }
    } else {                               // x(s+1) convert
        int tn = s + 1;
        if (tn < T_) {
            for (int i = (blk - 1536) * 256 + tid; i < B_ * IN_; i += 32 * 256) {
                int b = i >> 9, j = i & 511;
                float v = p.x[((size_t)b * T_ + tn) * IN_ + j];
                split2(v, &p.a10h[tn & 3][(size_t)b * K1P_ + j],
                          &p.a10l[tn & 3][(size_t)b * K1P_ + j]);
            }
        }
    }
}

// ---------------------------------------------------------------------------
// Setup kernels
// ---------------------------------------------------------------------------
__global__ __launch_bounds__(256) void conv_hi(
    const float* __restrict__ s1, int K1, const float* __restrict__ s2, int K2,
    int Nsrc, __bf16* __restrict__ hi, int Kd)
{
    int k = blockIdx.x * 256 + threadIdx.x;
    int n = blockIdx.y;
    if (k >= Kd) return;
    float v = 0.f;
    if (n < Nsrc) {
        if (k < K1) v = s1[(size_t)n * K1 + k];
        else if (k < K1 + K2) v = s2[(size_t)n * K2 + (k - K1)];
    }
    hi[(size_t)n * Kd + k] = (__bf16)v;
}

__global__ __launch_bounds__(256) void build_inp(const float* __restrict__ x,
                                                 __bf16* __restrict__ a1h,
                                                 __bf16* __restrict__ a1l)
{
    int idx = blockIdx.x * 256 + threadIdx.x;
    if (idx >= B_ * IN_) return;
    int b = idx >> 9, j = idx & 511;
    float v = x[(size_t)b * T_ * IN_ + j];
    split2(v, &a1h[b * K1P_ + j], &a1l[b * K1P_ + j]);
}

// ---------------------------------------------------------------------------
extern "C" void kernel_launch(void* const* d_in, const int* in_sizes, int n_in,
                              void* d_out, int out_size, void* d_ws, size_t ws_size,
                              hipStream_t stream)
{
    const float* x       = (const float*)d_in[0];
    const float* W_ih0   = (const float*)d_in[1];
    const float* W_hh0   = (const float*)d_in[2];
    const float* b_ih0   = (const float*)d_in[3];
    const float* b_hh0   = (const float*)d_in[4];
    const float* W_ih1   = (const float*)d_in[5];
    const float* W_hh1   = (const float*)d_in[6];
    const float* b_ih1   = (const float*)d_in[7];
    const float* b_hh1   = (const float*)d_in[8];
    const float* W_iface = (const float*)d_in[9];
    const float* b_iface = (const float*)d_in[10];
    const float* W_out   = (const float*)d_in[11];
    const float* b_out   = (const float*)d_in[12];

    P p;
    p.x = x;
    p.bih0 = b_ih0; p.bhh0 = b_hh0; p.bih1 = b_ih1; p.bhh1 = b_hh1;
    p.Wif0 = W_iface; p.Wif1 = W_iface + (size_t)IFACE_ * H_;
    p.bif0 = b_iface; p.bif1 = b_iface + IFACE_;
    p.bout = b_out;
    p.out = (float*)d_out;

    char* ptr = (char*)d_ws;
    auto alloc = [&](size_t bytes) { char* r = ptr; ptr += (bytes + 255) & ~(size_t)255; return r; };

    // ---- zero zone (memset each call) ----
    char* zstart = ptr;
    for (int q = 0; q < 4; ++q) { p.a10h[q] = (__bf16*)alloc(B_ * K1P_ * 2); p.a10l[q] = (__bf16*)alloc(B_ * K1P_ * 2); }
    for (int q = 0; q < 4; ++q) { p.a11h[q] = (__bf16*)alloc(B_ * K1P_ * 2); p.a11l[q] = (__bf16*)alloc(B_ * K1P_ * 2); }
    for (int q = 0; q < 4; ++q) { p.a20h[q] = (__bf16*)alloc(B_ * K2P_ * 2); p.a20l[q] = (__bf16*)alloc(B_ * K2P_ * 2); }
    for (int q = 0; q < 4; ++q) { p.a21h[q] = (__bf16*)alloc(B_ * K2P_ * 2); p.a21l[q] = (__bf16*)alloc(B_ * K2P_ * 2); }
    for (int q = 0; q < 4; ++q) { p.yh[q]  = (__bf16*)alloc(B_ * KOP_ * 2);  p.yl[q]  = (__bf16*)alloc(B_ * KOP_ * 2); }
    p.c00 = (float*)alloc((size_t)B_ * H_ * 4);
    p.c01 = (float*)alloc((size_t)B_ * H_ * 4);
    p.c10 = (float*)alloc((size_t)B_ * H_ * 4);
    p.c11 = (float*)alloc((size_t)B_ * H_ * 4);
    p.mem0  = (float*)alloc((size_t)B_ * M_ * WC_ * 4);
    p.link0 = (float*)alloc((size_t)B_ * M_ * M_ * 4);
    p.prec0 = (float*)alloc((size_t)B_ * M_ * 4);
    p.rw0   = (float*)alloc((size_t)B_ * R_ * M_ * 4);
    p.ww0   = (float*)alloc((size_t)B_ * M_ * 4);
    p.us0   = (float*)alloc((size_t)B_ * M_ * 4);
    p.mem1  = (float*)alloc((size_t)B_ * M_ * WC_ * 4);
    p.link1 = (float*)alloc((size_t)B_ * M_ * M_ * 4);
    p.prec1 = (float*)alloc((size_t)B_ * M_ * 4);
    p.rw1   = (float*)alloc((size_t)B_ * R_ * M_ * 4);
    p.ww1   = (float*)alloc((size_t)B_ * M_ * 4);
    p.us1   = (float*)alloc((size_t)B_ * M_ * 4);
    size_t zbytes = (size_t)(ptr - zstart);

    // ---- weights, single bf16 limb (rewritten every call) ----
    p.w10 = (__bf16*)alloc(2048ull * K1P_ * 2);
    p.w11 = (__bf16*)alloc(2048ull * K1P_ * 2);
    p.w20 = (__bf16*)alloc(2048ull * K2P_ * 2);
    p.w21 = (__bf16*)alloc(2048ull * K2P_ * 2);
    p.wo  = (__bf16*)alloc(512ull * KOP_ * 2);

    hipMemsetAsync(zstart, 0, zbytes, stream);

    conv_hi<<<dim3((K1P_ + 255) / 256, 2048), 256, 0, stream>>>(
        W_ih0, NNIN_, W_hh0, H_, 2048, p.w10, K1P_);
    conv_hi<<<dim3((K1P_ + 255) / 256, 2048), 256, 0, stream>>>(
        W_ih0 + 2048ull * NNIN_, NNIN_, W_hh0 + 2048ull * H_, H_, 2048, p.w11, K1P_);
    conv_hi<<<dim3((K2P_ + 255) / 256, 2048), 256, 0, stream>>>(
        W_ih1, H_, W_hh1, H_, 2048, p.w20, K2P_);
    conv_hi<<<dim3((K2P_ + 255) / 256, 2048), 256, 0, stream>>>(
        W_ih1 + 2048ull * H_, H_, W_hh1 + 2048ull * H_, H_, 2048, p.w21, K2P_);
    conv_hi<<<dim3((KOP_ + 255) / 256, 512), 256, 0, stream>>>(
        W_out, NNIN_, nullptr, 0, 512, p.wo, KOP_);
    build_inp<<<(B_ * IN_ + 255) / 256, 256, 0, stream>>>(x, p.a10h[0], p.a10l[0]);

    // 38 pipeline slots cover t=0..31 for all 7 stages
    for (int s = 0; s < T_ + 6; ++s) {
        slot_kernel<<<1568, 256, 0, stream>>>(p, s);
    }
}